// Round 22
// baseline (303.084 us; speedup 1.0000x reference)
//
#include <hip/hip_runtime.h>
#include <stdint.h>
#include <math.h>

// DeeperGNN forward on MI355X.
// R22 = R21 + edge-encoder A-gather: blocks process CSR positions, A rows
// gathered via csr_es[pos].x (scatter moved to 33.5MB read side), e_csr
// write fully linear. Per-row math identical to R21.

typedef __bf16 bf16x8 __attribute__((ext_vector_type(8)));
typedef __bf16 bf16x4 __attribute__((ext_vector_type(4)));
typedef float  f32x4  __attribute__((ext_vector_type(4)));

constexpr int NN   = 16384;   // nodes
constexpr int NE   = 131072;  // edges
constexpr int DIN  = 128;
constexpr int DE   = 64;
constexpr int HD   = 256;
constexpr int HD2  = 512;

__device__ __forceinline__ void gl_lds16(const __bf16* g, __bf16* l) {
  __builtin_amdgcn_global_load_lds((const __attribute__((address_space(1))) void*)g,
                                   (__attribute__((address_space(3))) void*)l, 16, 0, 0);
}

// ---------------- CSR build ----------------
__global__ __launch_bounds__(1024) void k_scan(const int* __restrict__ deg,
                                               int* __restrict__ row_start) {
  __shared__ int part[1024];
  const int t = threadIdx.x;
  const int base = t * 16;
  int loc[16];
  int s = 0;
  #pragma unroll
  for (int i = 0; i < 16; i++) { loc[i] = s; s += deg[base + i]; }
  part[t] = s;
  __syncthreads();
  for (int off = 1; off < 1024; off <<= 1) {
    int v = (t >= off) ? part[t - off] : 0;
    __syncthreads();
    part[t] += v;
    __syncthreads();
  }
  const int excl = (t == 0) ? 0 : part[t - 1];
  #pragma unroll
  for (int i = 0; i < 16; i++) row_start[base + i] = excl + loc[i];
}

__global__ void k_scatter(const int* __restrict__ src, const int* __restrict__ dst,
                          const int* __restrict__ row_start, int* __restrict__ cursor,
                          int2* __restrict__ csr_es) {
  int e = blockIdx.x * 256 + threadIdx.x;
  if (e >= NE) return;
  const int d = dst[e];
  const int p = atomicAdd(&cursor[d], 1);
  csr_es[row_start[d] + p] = make_int2(e, src[e]);
}

// wave-parallel canonical sort
__global__ __launch_bounds__(256)
void k_sortw(const int* __restrict__ row_start, const int* __restrict__ deg,
             int2* __restrict__ csr_es) {
  const int wv   = threadIdx.x >> 6;
  const int lane = threadIdx.x & 63;
  const int node = blockIdx.x * 4 + wv;
  if (node >= NN) return;
  const int st = __builtin_amdgcn_readfirstlane(row_start[node]);
  const int dg = __builtin_amdgcn_readfirstlane(deg[node]);
  if (dg <= 1) return;
  if (dg <= 64) {
    int2 pr = make_int2(0x7fffffff, 0);
    if (lane < dg) pr = csr_es[st + lane];
    int rank = 0;
    for (int j = 0; j < dg; j++) {
      const int ej = __builtin_amdgcn_readlane(pr.x, j);
      if (lane < dg && ej < pr.x) rank++;
    }
    if (lane < dg) csr_es[st + rank] = pr;
  } else if (lane == 0) {  // cold fallback
    for (int a = 1; a < dg; a++) {
      int2 k = csr_es[st + a];
      int b = a - 1;
      while (b >= 0 && csr_es[st + b].x > k.x) { csr_es[st + b + 1] = csr_es[st + b]; b--; }
      csr_es[st + b + 1] = k;
    }
  }
}

// ---------------- prep: weight transposes + degree histogram ----------------
__global__ void k_prep(const float* __restrict__ enc_w, const float* __restrict__ ee_w,
                       const float* __restrict__ w1, const float* __restrict__ w2,
                       const int* __restrict__ dst, int* __restrict__ deg,
                       __bf16* __restrict__ enc_wT, __bf16* __restrict__ ee_wT,
                       __bf16* __restrict__ w1T, __bf16* __restrict__ w2T) {
  int i = blockIdx.x * 256 + threadIdx.x;
  const int S0 = DIN * HD, S1 = DE * HD, S2 = 4 * HD * HD2, S3 = 4 * HD2 * HD;
  if (i < S0) { int k = i / HD, n = i % HD; enc_wT[n * DIN + k] = (__bf16)enc_w[i]; return; }
  i -= S0;
  if (i < S1) { int k = i / HD, n = i % HD; ee_wT[n * DE + k] = (__bf16)ee_w[i]; return; }
  i -= S1;
  if (i < S2) {
    int l = i / (HD * HD2), r = i % (HD * HD2), k = r / HD2, n = r % HD2;
    w1T[(size_t)l * HD * HD2 + (size_t)n * HD + k] = (__bf16)w1[i]; return;
  }
  i -= S2;
  if (i < S3) {
    int l = i / (HD2 * HD), r = i % (HD2 * HD), k = r / HD, n = r % HD;
    w2T[(size_t)l * HD2 * HD + (size_t)n * HD2 + k] = (__bf16)w2[i]; return;
  }
  i -= S3;
  if (i < NE) { atomicAdd(&deg[dst[i]], 1); return; }
}

// ---------------- MFMA GEMM body (device), 128x128 tile, 3-buf pipeline ----------
// AGAT: gather A rows (f32) via es[pos].x (edge encoder CSR-position mode).
template <int RES, int OBF, int STATS, int AGAT, int AF32>
__device__ __forceinline__
void gemm_body(char* smem, int bid,
               const void* __restrict__ Ap, const __bf16* __restrict__ BT,
               const float* __restrict__ bias, const float* __restrict__ R,
               float* __restrict__ Cf, __bf16* __restrict__ Cb,
               const int2* __restrict__ es, float2* __restrict__ pstats,
               int M, int Nn, int K) {
  float (*sm)[132] = (float(*)[132])smem;          // 32*132*4 = 16896
  float* sbias     = (float*)(smem + 16896);
  float2 (*pst4)[32] = (float2(*)[32])(smem + 17408);
  const __bf16* Ab = (const __bf16*)Ap;
  const float*  Af = (const float*)Ap;
  const int tid  = threadIdx.x;
  const int lane = tid & 63;
  const int wave = tid >> 6;
  const int ntn  = Nn >> 7;
  const int bn   = (bid >> 3) % ntn;                 // XCD swizzle
  const int bm   = (bid & 7) + ((bid >> 3) / ntn) * 8;
  const size_t row0 = (size_t)bm * 128, col0 = (size_t)bn * 128;
  const int wr = (wave >> 1) * 64, wc = (wave & 1) * 64;
  const int ks = lane >> 4, fr = lane & 15;

  auto bufA = [&](int i) -> __bf16* { return (__bf16*)(smem + i * 8192); };
  auto bufB = [&](int i) -> __bf16* { return (__bf16*)(smem + 24576 + i * 8192); };

  f32x4 acc[4][4] = {};

  const int arow = tid >> 2;
  const int aksg = (tid & 3) ^ ((arow >> 1) & 3);
  size_t ar0, ar1;   // A source rows (gathered for AGAT)
  if (AGAT) {
    ar0 = (size_t)es[row0 + arow].x;
    ar1 = (size_t)es[row0 + arow + 64].x;
  } else {
    ar0 = row0 + arow;
    ar1 = row0 + arow + 64;
  }

  auto stageB = [&](__bf16* lb, int k0) {
    gl_lds16(BT + (col0 + arow) * K + k0 + aksg * 8, &lb[tid * 8]);
    gl_lds16(BT + (col0 + arow + 64) * K + k0 + aksg * 8, &lb[(tid + 256) * 8]);
  };
  auto stageA = [&](__bf16* la, int k0) {
    gl_lds16(Ab + ar0 * K + k0 + aksg * 8, &la[tid * 8]);
    gl_lds16(Ab + ar1 * K + k0 + aksg * 8, &la[(tid + 256) * 8]);
  };
  float4 p0, p1, q0, q1;
  auto loadAf = [&](int k0) {
    const float* a0p = &Af[ar0 * K + k0 + aksg * 8];
    const float* a1p = &Af[ar1 * K + k0 + aksg * 8];
    p0 = *(const float4*)a0p; p1 = *(const float4*)(a0p + 4);
    q0 = *(const float4*)a1p; q1 = *(const float4*)(a1p + 4);
  };
  auto writeAf = [&](__bf16* la) {
    bf16x8 o0, o1;
    o0[0] = (__bf16)p0.x; o0[1] = (__bf16)p0.y; o0[2] = (__bf16)p0.z; o0[3] = (__bf16)p0.w;
    o0[4] = (__bf16)p1.x; o0[5] = (__bf16)p1.y; o0[6] = (__bf16)p1.z; o0[7] = (__bf16)p1.w;
    o1[0] = (__bf16)q0.x; o1[1] = (__bf16)q0.y; o1[2] = (__bf16)q0.z; o1[3] = (__bf16)q0.w;
    o1[4] = (__bf16)q1.x; o1[5] = (__bf16)q1.y; o1[6] = (__bf16)q1.z; o1[7] = (__bf16)q1.w;
    *(bf16x8*)&la[tid * 8] = o0;
    *(bf16x8*)&la[(tid + 256) * 8] = o1;
  };

  int slA[4], slB[4];
  #pragma unroll
  for (int m = 0; m < 4; m++) {
    const int rm = wr + m * 16 + fr;
    slA[m] = rm * 4 + (ks ^ ((rm >> 1) & 3));
    const int cn = wc + m * 16 + fr;
    slB[m] = cn * 4 + (ks ^ ((cn >> 1) & 3));
  }

  const int nk = K / 32;
  if (AF32) { loadAf(0); stageB(bufB(0), 0); writeAf(bufA(0)); }
  else      { stageA(bufA(0), 0); stageB(bufB(0), 0); }
  if (nk > 1) {
    if (AF32) { loadAf(32); stageB(bufB(1), 32); writeAf(bufA(1)); }
    else      { stageA(bufA(1), 32); stageB(bufB(1), 32); }
  }
  for (int t = 0; t < nk; t++) {
    const int rem = nk - 1 - t;
    const int nb3 = (t + 2) % 3;
    if (rem >= 2) {
      if (AF32) { loadAf((t + 2) * 32); stageB(bufB(nb3), (t + 2) * 32); }
      else      { stageA(bufA(nb3), (t + 2) * 32); stageB(bufB(nb3), (t + 2) * 32); }
    }
    if (AF32) {
      if (rem >= 2)      asm volatile("s_waitcnt vmcnt(8) lgkmcnt(0)" ::: "memory");
      else if (rem == 1) asm volatile("s_waitcnt vmcnt(2) lgkmcnt(0)" ::: "memory");
      else               asm volatile("s_waitcnt vmcnt(0) lgkmcnt(0)" ::: "memory");
    } else {
      if (rem >= 2)      asm volatile("s_waitcnt vmcnt(8)" ::: "memory");
      else if (rem == 1) asm volatile("s_waitcnt vmcnt(4)" ::: "memory");
      else               asm volatile("s_waitcnt vmcnt(0)" ::: "memory");
    }
    __builtin_amdgcn_s_barrier();
    __builtin_amdgcn_sched_barrier(0);
    const __bf16* la = bufA(t % 3);
    const __bf16* lb = bufB(t % 3);
    bf16x8 af[4], bfr[4];
    #pragma unroll
    for (int m = 0; m < 4; m++) af[m]  = *(const bf16x8*)&la[slA[m] * 8];
    #pragma unroll
    for (int n = 0; n < 4; n++) bfr[n] = *(const bf16x8*)&lb[slB[n] * 8];
    #pragma unroll
    for (int m = 0; m < 4; m++)
      #pragma unroll
      for (int n = 0; n < 4; n++)
        acc[m][n] = __builtin_amdgcn_mfma_f32_16x16x32_bf16(af[m], bfr[n], acc[m][n], 0, 0, 0);
    if (AF32 && rem >= 2) writeAf(bufA(nb3));
    __builtin_amdgcn_s_barrier();
  }
  __syncthreads();

  // ---- coalesced epilogue (stride-132 sm, float4 readback) ----
  if (tid < 128) sbias[tid] = bias[col0 + tid];
  const int rbase = (wave >> 1) * 16 + ks * 4;
  const int rr = tid >> 3, cs = (tid & 7) * 16;
  #pragma unroll
  for (int m = 0; m < 4; m++) {
    if (m) __syncthreads();
    #pragma unroll
    for (int n = 0; n < 4; n++)
      #pragma unroll
      for (int r = 0; r < 4; r++)
        sm[rbase + r][wc + n * 16 + fr] = acc[m][n][r];
    __syncthreads();
    const size_t lrow = ((rr & 16) ? 64 : 0) + m * 16 + (rr & 15);
    const size_t grow = row0 + lrow;
    float v[16];
    #pragma unroll
    for (int j4 = 0; j4 < 4; j4++) {
      const float4 sv4 = *(const float4*)&sm[rr][cs + j4 * 4];
      v[j4 * 4]     = sv4.x + sbias[cs + j4 * 4];
      v[j4 * 4 + 1] = sv4.y + sbias[cs + j4 * 4 + 1];
      v[j4 * 4 + 2] = sv4.z + sbias[cs + j4 * 4 + 2];
      v[j4 * 4 + 3] = sv4.w + sbias[cs + j4 * 4 + 3];
    }
    if (STATS) {
      float ssum = 0.f, ssq = 0.f;
      #pragma unroll
      for (int j = 0; j < 16; j++) { ssum += v[j]; ssq += v[j] * v[j]; }
      #pragma unroll
      for (int o = 1; o < 8; o <<= 1) {
        ssum += __shfl_xor(ssum, o);
        ssq  += __shfl_xor(ssq, o);
      }
      if ((tid & 7) == 0) pst4[m][rr].x = ssum, pst4[m][rr].y = ssq;
    }
    const size_t gbase = grow * Nn + col0 + cs;
    if (RES) {
      #pragma unroll
      for (int j = 0; j < 16; j += 4) {
        const float4 rv = *(const float4*)&R[gbase + j];
        v[j] += rv.x; v[j + 1] += rv.y; v[j + 2] += rv.z; v[j + 3] += rv.w;
      }
    }
    if (OBF == 0 || OBF == 2) {
      #pragma unroll
      for (int j = 0; j < 16; j += 4) {
        float4 o; o.x = v[j]; o.y = v[j + 1]; o.z = v[j + 2]; o.w = v[j + 3];
        *(float4*)&Cf[gbase + j] = o;
      }
    }
    if (OBF == 1 || OBF == 2) {
      bf16x8 o0, o1;
      #pragma unroll
      for (int j = 0; j < 8; j++) { o0[j] = (__bf16)v[j]; o1[j] = (__bf16)v[8 + j]; }
      *(bf16x8*)&Cb[gbase] = o0;
      *(bf16x8*)&Cb[gbase + 8] = o1;
    }
  }
  if (STATS) {
    __syncthreads();
    if (tid < 128) {
      const int lr = tid;
      const int hi = lr >> 6, m2 = (lr >> 4) & 3, rl = lr & 15;
      pstats[(row0 + lr) * ntn + bn] = pst4[m2][(hi << 4) | rl];
    }
  }
}

// GEMM1 wrapper (bf16 A, bf16 C + stats)
__global__ __launch_bounds__(256, 3)
void k_gemm1(const __bf16* A, const __bf16* BT, const float* bias,
             __bf16* Cb, float2* pstats, int M, int Nn, int K) {
  __shared__ __attribute__((aligned(16))) char smem[49152];
  gemm_body<0, 1, 1, 0, 0>(smem, (int)blockIdx.x, A, BT, bias, nullptr,
                           nullptr, Cb, nullptr, pstats, M, Nn, K);
}

// combined encoders: blocks [0,2048) edge-enc (A gathered by CSR pos, linear C),
// blocks [2048,2304) node-enc (f32 A, dual f32+bf16 C).
__global__ __launch_bounds__(256, 3)
void k_encs(const float* x, const __bf16* enc_wT, const float* enc_b,
            float* h, __bf16* hb,
            const float* ea, const __bf16* ee_wT, const float* ee_b,
            __bf16* e_csr, const int2* csr_es) {
  __shared__ __attribute__((aligned(16))) char smem[49152];
  const int bid = (int)blockIdx.x;
  if (bid < (NE / 128) * (HD / 128)) {
    gemm_body<0, 1, 0, 1, 1>(smem, bid, ea, ee_wT, ee_b, nullptr,
                             nullptr, e_csr, csr_es, nullptr, NE, HD, DE);
  } else {
    gemm_body<0, 2, 0, 0, 1>(smem, bid - (NE / 128) * (HD / 128), x, enc_wT, enc_b,
                             nullptr, h, hb, nullptr, nullptr, NN, HD, DIN);
  }
}

// ---------------- GEMM2 full-row: 32x256 tile; LN(c1) on A-stage; epilogue
// computes h (+res) AND next-layer zb = bf16(relu(LN256(h))) in one pass. ----
template <int RES, int WH>
__global__ __launch_bounds__(256, 3)
void k_gemm2f(const __bf16* __restrict__ c1b, const __bf16* __restrict__ BT,
              const float* __restrict__ bias, const float* __restrict__ R,
              const float2* __restrict__ pstats, const float* __restrict__ gamma,
              const float* __restrict__ beta, const float* __restrict__ g2,
              const float* __restrict__ b2, float* __restrict__ hout,
              __bf16* __restrict__ zout) {
  constexpr int K = HD2;    // 512
  constexpr int NC = HD;    // 256
  __shared__ __attribute__((aligned(16))) char smem[7424 + 36864];
  float* smu  = (float*)smem;                   // 128
  float* sinv = (float*)(smem + 128);           // 128
  float* sg   = (float*)(smem + 256);           // 2048
  float* sb   = (float*)(smem + 2304);          // 2048
  float* sg2  = (float*)(smem + 4352);          // 1024
  float* sb2  = (float*)(smem + 5376);          // 1024
  float* sbias= (float*)(smem + 6400);          // 1024
  char* arena = smem + 7424;
  auto bufA = [&](int i) -> __bf16* { return (__bf16*)(arena + i * 18432); };
  auto bufB = [&](int i) -> __bf16* { return (__bf16*)(arena + i * 18432 + 2048); };
  float (*sm)[268] = (float(*)[268])arena;      // 32*268*4 = 34304 <= 36864

  const int tid = threadIdx.x, lane = tid & 63, wave = tid >> 6;
  const size_t row0 = (size_t)blockIdx.x * 32;
  const int wc = wave * 64;
  const int ks = lane >> 4, fr = lane & 15;

  if (tid < 32) {
    const float4* pp = (const float4*)&pstats[(row0 + tid) * 4];
    const float4 a0 = pp[0], a1 = pp[1];
    const float su = a0.x + a0.z + a1.x + a1.z;
    const float sq = a0.y + a0.w + a1.y + a1.w;
    const float mu = su * (1.f / K);
    smu[tid] = mu;
    sinv[tid] = rsqrtf(sq * (1.f / K) - mu * mu + 1e-5f);
  }
  sg[tid] = gamma[tid]; sg[tid + 256] = gamma[tid + 256];
  sb[tid] = beta[tid];  sb[tid + 256] = beta[tid + 256];
  sg2[tid] = g2[tid]; sb2[tid] = b2[tid]; sbias[tid] = bias[tid];
  __syncthreads();

  const int arow = tid >> 2;                 // A row for t<128 (0..31)
  const int akg  = (tid & 3) ^ ((arow >> 1) & 3);
  f32x4 acc[2][4] = {};
  bf16x8 aReg;

  auto stageB = [&](__bf16* lb, int k0) {
    #pragma unroll
    for (int j = 0; j < 4; j++) {
      const int s = j * 256 + tid;
      const int scol = s >> 2;
      const int kg = (s & 3) ^ ((scol >> 1) & 3);
      gl_lds16(BT + (size_t)scol * K + k0 + kg * 8, &lb[s * 8]);
    }
  };
  auto loadA = [&](int k0) {
    if (tid < 128) aReg = *(const bf16x8*)&c1b[(row0 + arow) * K + k0 + akg * 8];
  };
  auto writeA = [&](__bf16* la, int k0) {
    if (tid < 128) {
      const int kb = k0 + akg * 8;
      const float mu = smu[arow], iv = sinv[arow];
      bf16x8 o;
      #pragma unroll
      for (int j = 0; j < 8; j++) {
        const float f = ((float)aReg[j] - mu) * iv * sg[kb + j] + sb[kb + j];
        o[j] = (__bf16)fmaxf(f, 0.f);
      }
      *(bf16x8*)&la[tid * 8] = o;
    }
  };

  int slA[2], slB[4];
  #pragma unroll
  for (int m = 0; m < 2; m++) {
    const int rm = m * 16 + fr;
    slA[m] = rm * 4 + (ks ^ ((rm >> 1) & 3));
  }
  #pragma unroll
  for (int n = 0; n < 4; n++) {
    const int cn = wc + n * 16 + fr;
    slB[n] = cn * 4 + (ks ^ ((cn >> 1) & 3));
  }

  const int nk = K / 32;   // 16
  loadA(0); stageB(bufB(0), 0); writeA(bufA(0), 0);
  for (int t = 0; t < nk; t++) {
    const bool more = (t + 1 < nk);
    const int cur = t & 1;
    if (more) { stageB(bufB(cur ^ 1), (t + 1) * 32); loadA((t + 1) * 32); }
    if (more) {
      if (wave < 2) asm volatile("s_waitcnt vmcnt(5) lgkmcnt(0)" ::: "memory");
      else          asm volatile("s_waitcnt vmcnt(4) lgkmcnt(0)" ::: "memory");
    } else {
      asm volatile("s_waitcnt vmcnt(0) lgkmcnt(0)" ::: "memory");
    }
    __builtin_amdgcn_s_barrier();
    __builtin_amdgcn_sched_barrier(0);
    const __bf16* la = bufA(cur);
    const __bf16* lb = bufB(cur);
    bf16x8 af[2], bfr[4];
    #pragma unroll
    for (int m = 0; m < 2; m++) af[m]  = *(const bf16x8*)&la[slA[m] * 8];
    #pragma unroll
    for (int n = 0; n < 4; n++) bfr[n] = *(const bf16x8*)&lb[slB[n] * 8];
    #pragma unroll
    for (int m = 0; m < 2; m++)
      #pragma unroll
      for (int n = 0; n < 4; n++)
        acc[m][n] = __builtin_amdgcn_mfma_f32_16x16x32_bf16(af[m], bfr[n], acc[m][n], 0, 0, 0);
    if (more) writeA(bufA(cur ^ 1), (t + 1) * 32);
    __builtin_amdgcn_s_barrier();
  }
  __syncthreads();

  // ---- epilogue: transpose to sm (stride 268), LN over 256 cols, emit h+zb ----
  #pragma unroll
  for (int m = 0; m < 2; m++)
    #pragma unroll
    for (int n = 0; n < 4; n++)
      #pragma unroll
      for (int r = 0; r < 4; r++)
        sm[m * 16 + ks * 4 + r][wc + n * 16 + fr] = acc[m][n][r];
  __syncthreads();
  const int rr = tid >> 3, c0 = (tid & 7) * 4;
  float v[32];
  float s = 0.f, sq = 0.f;
  #pragma unroll
  for (int j = 0; j < 8; j++) {
    const int c = c0 + j * 32;
    const float4 sv4 = *(const float4*)&sm[rr][c];
    float x0 = sv4.x + sbias[c];
    float x1 = sv4.y + sbias[c + 1];
    float x2 = sv4.z + sbias[c + 2];
    float x3 = sv4.w + sbias[c + 3];
    if (RES) {
      const float4 rv = *(const float4*)&R[(row0 + rr) * NC + c];
      x0 += rv.x; x1 += rv.y; x2 += rv.z; x3 += rv.w;
    }
    v[j * 4] = x0; v[j * 4 + 1] = x1; v[j * 4 + 2] = x2; v[j * 4 + 3] = x3;
    s += x0 + x1 + x2 + x3;
    sq += x0 * x0 + x1 * x1 + x2 * x2 + x3 * x3;
  }
  #pragma unroll
  for (int o = 1; o < 8; o <<= 1) { s += __shfl_xor(s, o); sq += __shfl_xor(sq, o); }
  const float mu = s * (1.f / NC);
  const float inv = rsqrtf(sq * (1.f / NC) - mu * mu + 1e-5f);
  #pragma unroll
  for (int j = 0; j < 8; j++) {
    const int c = c0 + j * 32;
    if (WH) {
      float4 o;
      o.x = v[j * 4]; o.y = v[j * 4 + 1]; o.z = v[j * 4 + 2]; o.w = v[j * 4 + 3];
      *(float4*)&hout[(row0 + rr) * NC + c] = o;
    }
    bf16x4 z;
    z[0] = (__bf16)fmaxf((v[j * 4]     - mu) * inv * sg2[c]     + sb2[c],     0.f);
    z[1] = (__bf16)fmaxf((v[j * 4 + 1] - mu) * inv * sg2[c + 1] + sb2[c + 1], 0.f);
    z[2] = (__bf16)fmaxf((v[j * 4 + 2] - mu) * inv * sg2[c + 2] + sb2[c + 2], 0.f);
    z[3] = (__bf16)fmaxf((v[j * 4 + 3] - mu) * inv * sg2[c + 3] + sb2[c + 3], 0.f);
    *(bf16x4*)&zout[(row0 + rr) * NC + c] = z;
  }
}

// ---------------- wave-per-node softmax aggregation (8-deep groups, bf16 zb) ----
__global__ __launch_bounds__(256)
void k_msg(const __bf16* __restrict__ zb, const __bf16* __restrict__ ecsr,
           const int* __restrict__ row_start, const int* __restrict__ deg,
           const int2* __restrict__ csr_es, const float* __restrict__ tvec,
           int layer, __bf16* __restrict__ a1) {
  const int wv   = __builtin_amdgcn_readfirstlane(threadIdx.x >> 6);
  const int lane = threadIdx.x & 63;
  const int node = blockIdx.x * 4 + wv;
  const int st = __builtin_amdgcn_readfirstlane(row_start[node]);
  const int dg = __builtin_amdgcn_readfirstlane(deg[node]);
  const float t = tvec[layer];
  const int f0 = lane * 4;

  int my_src = 0;
  if (lane < dg) my_src = csr_es[st + lane].y;
  const bf16x4 sv = *(const bf16x4*)&zb[(size_t)node * HD + f0];

  float den[4] = {0.f, 0.f, 0.f, 0.f}, agg[4] = {0.f, 0.f, 0.f, 0.f};
  const int dmain = dg < 64 ? dg : 64;
  int j = 0;
  for (; j + 8 <= dmain; j += 8) {
    bf16x4 zv[8], ev[8];
    #pragma unroll
    for (int u = 0; u < 8; u++) {
      const int sn = __builtin_amdgcn_readlane(my_src, j + u);
      zv[u] = *(const bf16x4*)&zb[(size_t)sn * HD + f0];
      ev[u] = *(const bf16x4*)&ecsr[(size_t)(st + j + u) * HD + f0];
    }
    #pragma unroll
    for (int u = 0; u < 8; u++)
      #pragma unroll
      for (int q = 0; q < 4; q++) {
        const float m  = fmaxf((float)zv[u][q] + (float)ev[u][q], 0.f) + 1e-7f;
        const float ex = __expf(m * t);
        den[q] += ex;
        agg[q] += m * ex;
      }
  }
  for (; j + 4 <= dmain; j += 4) {
    bf16x4 zv[4], ev[4];
    #pragma unroll
    for (int u = 0; u < 4; u++) {
      const int sn = __builtin_amdgcn_readlane(my_src, j + u);
      zv[u] = *(const bf16x4*)&zb[(size_t)sn * HD + f0];
      ev[u] = *(const bf16x4*)&ecsr[(size_t)(st + j + u) * HD + f0];
    }
    #pragma unroll
    for (int u = 0; u < 4; u++)
      #pragma unroll
      for (int q = 0; q < 4; q++) {
        const float m  = fmaxf((float)zv[u][q] + (float)ev[u][q], 0.f) + 1e-7f;
        const float ex = __expf(m * t);
        den[q] += ex;
        agg[q] += m * ex;
      }
  }
  for (; j < dmain; j++) {
    const int sn = __builtin_amdgcn_readlane(my_src, j);
    const bf16x4 zv = *(const bf16x4*)&zb[(size_t)sn * HD + f0];
    const bf16x4 ev = *(const bf16x4*)&ecsr[(size_t)(st + j) * HD + f0];
    #pragma unroll
    for (int q = 0; q < 4; q++) {
      const float m  = fmaxf((float)zv[q] + (float)ev[q], 0.f) + 1e-7f;
      const float ex = __expf(m * t);
      den[q] += ex;
      agg[q] += m * ex;
    }
  }
  for (int jj = 64; jj < dg; jj++) {  // cold path
    const int2 pr = csr_es[st + jj];
    const bf16x4 zv = *(const bf16x4*)&zb[(size_t)pr.y * HD + f0];
    const bf16x4 ev = *(const bf16x4*)&ecsr[(size_t)(st + jj) * HD + f0];
    #pragma unroll
    for (int q = 0; q < 4; q++) {
      const float m  = fmaxf((float)zv[q] + (float)ev[q], 0.f) + 1e-7f;
      const float ex = __expf(m * t);
      den[q] += ex;
      agg[q] += m * ex;
    }
  }
  bf16x4 r;
  #pragma unroll
  for (int q = 0; q < 4; q++) {
    const float res = (dg > 0) ? agg[q] / (den[q] + 1e-16f) : 0.f;
    r[q] = (__bf16)(res + (float)sv[q]);
  }
  *(bf16x4*)&a1[(size_t)node * HD + f0] = r;
}

// ---------------- head: out = zb @ lin_w + lin_b ----------------
__global__ __launch_bounds__(256)
void k_head(const __bf16* __restrict__ zb, const float* __restrict__ lw,
            const float* __restrict__ lb, float* __restrict__ out) {
  __shared__ float slw[256 * 16];     // [k][c]
  __shared__ __bf16 srow[16 * 256];
  const int t = threadIdx.x;
  const size_t row0 = (size_t)blockIdx.x * 16;
  #pragma unroll
  for (int j = 0; j < 16; j++) slw[j * 256 + t] = lw[j * 256 + t];
  #pragma unroll
  for (int j = 0; j < 2; j++) {
    const int c = j * 256 + t;
    ((bf16x8*)srow)[c] = ((const bf16x8*)(zb + row0 * 256))[c];
  }
  __syncthreads();
  const int rl = t >> 4, col = t & 15;
  float s = lb[col];
  for (int k0 = 0; k0 < 256; k0 += 8) {
    const bf16x8 zv = *(const bf16x8*)&srow[rl * 256 + k0];
    #pragma unroll
    for (int q = 0; q < 8; q++) s += (float)zv[q] * slw[(k0 + q) * 16 + col];
  }
  out[(row0 + rl) * 16 + col] = s;
}

// ---------------- host launch ----------------
extern "C" void kernel_launch(void* const* d_in, const int* in_sizes, int n_in,
                              void* d_out, int out_size, void* d_ws, size_t ws_size,
                              hipStream_t stream) {
  const float* x     = (const float*)d_in[0];
  const int*   ei    = (const int*)d_in[1];
  const float* ea    = (const float*)d_in[2];
  const float* enc_w = (const float*)d_in[3];
  const float* enc_b = (const float*)d_in[4];
  const float* ee_w  = (const float*)d_in[5];
  const float* ee_b  = (const float*)d_in[6];
  const float* w1    = (const float*)d_in[7];
  const float* b1    = (const float*)d_in[8];
  const float* lng   = (const float*)d_in[9];
  const float* lnb   = (const float*)d_in[10];
  const float* w2    = (const float*)d_in[11];
  const float* b2    = (const float*)d_in[12];
  const float* tvec  = (const float*)d_in[13];
  const float* ng    = (const float*)d_in[14];
  const float* nb    = (const float*)d_in[15];
  const float* lin_w = (const float*)d_in[16];
  const float* lin_b = (const float*)d_in[17];

  uint8_t* p = (uint8_t*)d_ws;
  auto alloc = [&](size_t bytes) { uint8_t* r = p; p += (bytes + 255) & ~(size_t)255; return r; };
  __bf16* e_csr  = (__bf16*)alloc((size_t)NE * HD * 2);
  float*  h      = (float*) alloc((size_t)NN * HD * 4);
  __bf16* hb     = (__bf16*)alloc((size_t)NN * HD * 2);
  __bf16* zb     = (__bf16*)alloc((size_t)NN * HD * 2);
  __bf16* a1     = (__bf16*)alloc((size_t)NN * HD * 2);
  __bf16* c1b    = (__bf16*)alloc((size_t)NN * HD2 * 2);
  float2* pstats = (float2*)alloc((size_t)NN * 4 * 8);
  __bf16* enc_wT = (__bf16*)alloc((size_t)HD * DIN * 2);
  __bf16* ee_wT  = (__bf16*)alloc((size_t)HD * DE * 2);
  __bf16* w1T    = (__bf16*)alloc((size_t)4 * HD2 * HD * 2);
  __bf16* w2T    = (__bf16*)alloc((size_t)4 * HD * HD2 * 2);
  int* deg       = (int*)alloc((size_t)NN * 4);
  int* cursor    = (int*)alloc((size_t)NN * 4);   // contiguous with deg -> one memset
  int* row_start = (int*)alloc((size_t)NN * 4);
  int2* csr_es   = (int2*)alloc((size_t)NE * 8);

  const int* srcp = ei;
  const int* dstp = ei + NE;

  hipMemsetAsync(deg, 0, (size_t)NN * 8, stream);  // deg + cursor

  const int prep_total = DIN * HD + DE * HD + 4 * HD * HD2 + 4 * HD2 * HD + NE;
  k_prep<<<(prep_total + 255) / 256, 256, 0, stream>>>(enc_w, ee_w, w1, w2, dstp, deg,
                                                       enc_wT, ee_wT, w1T, w2T);
  k_scan<<<1, 1024, 0, stream>>>(deg, row_start);
  k_scatter<<<NE / 256, 256, 0, stream>>>(srcp, dstp, row_start, cursor, csr_es);
  k_sortw<<<NN / 4, 256, 0, stream>>>(row_start, deg, csr_es);

  // both encoders in one launch: edge-enc (2048 blocks, A gathered) || node-enc
  k_encs<<<(NE / 128) * (HD / 128) + (NN / 128) * (HD / 128), 256, 0, stream>>>(
      x, enc_wT, enc_b, h, hb, ea, ee_wT, ee_b, e_csr, csr_es);

  for (int i = 0; i < 4; i++) {
    const __bf16* zin = (i == 0) ? hb : zb;
    k_msg<<<NN / 4, 256, 0, stream>>>(zin, e_csr, row_start, deg, csr_es, tvec, i, a1);
    // GEMM1: c1b = bf16(a1 @ w1 + b1) + 512-wide row stats
    k_gemm1<<<(NN / 128) * (HD2 / 128), 256, 0, stream>>>(
        a1, w1T + (size_t)i * HD2 * HD, b1 + (size_t)i * HD2, c1b, pstats, NN, HD2, HD);
    // GEMM2 full-row: h (+res) AND next-layer zb in one epilogue
    const int nidx = (i < 3) ? i + 1 : 0;
    const float* gg = ng + (size_t)nidx * HD;
    const float* bb = nb + (size_t)nidx * HD;
    if (i == 0)
      k_gemm2f<0, 1><<<NN / 32, 256, 0, stream>>>(
          c1b, w2T + (size_t)i * HD * HD2, b2 + (size_t)i * HD, nullptr, pstats,
          lng + (size_t)i * HD2, lnb + (size_t)i * HD2, gg, bb, h, zb);
    else if (i < 3)
      k_gemm2f<1, 1><<<NN / 32, 256, 0, stream>>>(
          c1b, w2T + (size_t)i * HD * HD2, b2 + (size_t)i * HD, h, pstats,
          lng + (size_t)i * HD2, lnb + (size_t)i * HD2, gg, bb, h, zb);
    else
      k_gemm2f<1, 0><<<NN / 32, 256, 0, stream>>>(
          c1b, w2T + (size_t)i * HD * HD2, b2 + (size_t)i * HD, h, pstats,
          lng + (size_t)i * HD2, lnb + (size_t)i * HD2, gg, bb, h, zb);
  }

  k_head<<<NN / 16, 256, 0, stream>>>(zb, lin_w, lin_b, (float*)d_out);
}

// Round 23
// 300.876 us; speedup vs baseline: 1.0073x; 1.0073x over previous
//
#include <hip/hip_runtime.h>
#include <stdint.h>
#include <math.h>

// DeeperGNN forward on MI355X.
// R23 = R22 + k_encs2: encoder GEMM specialized for tiny K — all-of-K staged
// upfront (2x(A,B) 8KB bufs, 32KB LDS), one barrier, no pipeline; 4 blocks/CU.

typedef __bf16 bf16x8 __attribute__((ext_vector_type(8)));
typedef __bf16 bf16x4 __attribute__((ext_vector_type(4)));
typedef float  f32x4  __attribute__((ext_vector_type(4)));

constexpr int NN   = 16384;   // nodes
constexpr int NE   = 131072;  // edges
constexpr int DIN  = 128;
constexpr int DE   = 64;
constexpr int HD   = 256;
constexpr int HD2  = 512;

__device__ __forceinline__ void gl_lds16(const __bf16* g, __bf16* l) {
  __builtin_amdgcn_global_load_lds((const __attribute__((address_space(1))) void*)g,
                                   (__attribute__((address_space(3))) void*)l, 16, 0, 0);
}

// ---------------- CSR build ----------------
__global__ __launch_bounds__(1024) void k_scan(const int* __restrict__ deg,
                                               int* __restrict__ row_start) {
  __shared__ int part[1024];
  const int t = threadIdx.x;
  const int base = t * 16;
  int loc[16];
  int s = 0;
  #pragma unroll
  for (int i = 0; i < 16; i++) { loc[i] = s; s += deg[base + i]; }
  part[t] = s;
  __syncthreads();
  for (int off = 1; off < 1024; off <<= 1) {
    int v = (t >= off) ? part[t - off] : 0;
    __syncthreads();
    part[t] += v;
    __syncthreads();
  }
  const int excl = (t == 0) ? 0 : part[t - 1];
  #pragma unroll
  for (int i = 0; i < 16; i++) row_start[base + i] = excl + loc[i];
}

__global__ void k_scatter(const int* __restrict__ src, const int* __restrict__ dst,
                          const int* __restrict__ row_start, int* __restrict__ cursor,
                          int2* __restrict__ csr_es) {
  int e = blockIdx.x * 256 + threadIdx.x;
  if (e >= NE) return;
  const int d = dst[e];
  const int p = atomicAdd(&cursor[d], 1);
  csr_es[row_start[d] + p] = make_int2(e, src[e]);
}

// wave-parallel canonical sort
__global__ __launch_bounds__(256)
void k_sortw(const int* __restrict__ row_start, const int* __restrict__ deg,
             int2* __restrict__ csr_es) {
  const int wv   = threadIdx.x >> 6;
  const int lane = threadIdx.x & 63;
  const int node = blockIdx.x * 4 + wv;
  if (node >= NN) return;
  const int st = __builtin_amdgcn_readfirstlane(row_start[node]);
  const int dg = __builtin_amdgcn_readfirstlane(deg[node]);
  if (dg <= 1) return;
  if (dg <= 64) {
    int2 pr = make_int2(0x7fffffff, 0);
    if (lane < dg) pr = csr_es[st + lane];
    int rank = 0;
    for (int j = 0; j < dg; j++) {
      const int ej = __builtin_amdgcn_readlane(pr.x, j);
      if (lane < dg && ej < pr.x) rank++;
    }
    if (lane < dg) csr_es[st + rank] = pr;
  } else if (lane == 0) {  // cold fallback
    for (int a = 1; a < dg; a++) {
      int2 k = csr_es[st + a];
      int b = a - 1;
      while (b >= 0 && csr_es[st + b].x > k.x) { csr_es[st + b + 1] = csr_es[st + b]; b--; }
      csr_es[st + b + 1] = k;
    }
  }
}

// ---------------- prep: weight transposes + degree histogram ----------------
__global__ void k_prep(const float* __restrict__ enc_w, const float* __restrict__ ee_w,
                       const float* __restrict__ w1, const float* __restrict__ w2,
                       const int* __restrict__ dst, int* __restrict__ deg,
                       __bf16* __restrict__ enc_wT, __bf16* __restrict__ ee_wT,
                       __bf16* __restrict__ w1T, __bf16* __restrict__ w2T) {
  int i = blockIdx.x * 256 + threadIdx.x;
  const int S0 = DIN * HD, S1 = DE * HD, S2 = 4 * HD * HD2, S3 = 4 * HD2 * HD;
  if (i < S0) { int k = i / HD, n = i % HD; enc_wT[n * DIN + k] = (__bf16)enc_w[i]; return; }
  i -= S0;
  if (i < S1) { int k = i / HD, n = i % HD; ee_wT[n * DE + k] = (__bf16)ee_w[i]; return; }
  i -= S1;
  if (i < S2) {
    int l = i / (HD * HD2), r = i % (HD * HD2), k = r / HD2, n = r % HD2;
    w1T[(size_t)l * HD * HD2 + (size_t)n * HD + k] = (__bf16)w1[i]; return;
  }
  i -= S2;
  if (i < S3) {
    int l = i / (HD2 * HD), r = i % (HD2 * HD), k = r / HD, n = r % HD;
    w2T[(size_t)l * HD2 * HD + (size_t)n * HD2 + k] = (__bf16)w2[i]; return;
  }
  i -= S3;
  if (i < NE) { atomicAdd(&deg[dst[i]], 1); return; }
}

// ---------------- encoder GEMM body: tiny-K, all-K staged, no pipeline ----------
// KK = full K (64 or 128). OBF: 1=bf16 C, 2=dual f32+bf16. AGAT: gather A rows.
template <int OBF, int AGAT, int KK>
__device__ __forceinline__
void encs_body(char* smem, int bid,
               const float* __restrict__ Af, const __bf16* __restrict__ BT,
               const float* __restrict__ bias, float* __restrict__ Cf,
               __bf16* __restrict__ Cb, const int2* __restrict__ es, int Nn) {
  float (*sm)[132] = (float(*)[132])smem;          // epilogue overlay (16896B)
  float* sbias     = (float*)(smem + 16896);       // 512B
  const int tid  = threadIdx.x;
  const int lane = tid & 63;
  const int wave = tid >> 6;
  const int ntn  = Nn >> 7;
  const int bn   = (bid >> 3) % ntn;                 // XCD swizzle
  const int bm   = (bid & 7) + ((bid >> 3) / ntn) * 8;
  const size_t row0 = (size_t)bm * 128, col0 = (size_t)bn * 128;
  const int wr = (wave >> 1) * 64, wc = (wave & 1) * 64;
  const int ks = lane >> 4, fr = lane & 15;

  auto bufA = [&](int i) -> __bf16* { return (__bf16*)(smem + i * 8192); };
  auto bufB = [&](int i) -> __bf16* { return (__bf16*)(smem + 16384 + i * 8192); };

  f32x4 acc[4][4] = {};

  const int arow = tid >> 2;
  const int aksg = (tid & 3) ^ ((arow >> 1) & 3);
  size_t ar0, ar1;
  if (AGAT) {
    ar0 = (size_t)es[row0 + arow].x;
    ar1 = (size_t)es[row0 + arow + 64].x;
  } else {
    ar0 = row0 + arow;
    ar1 = row0 + arow + 64;
  }

  auto stageB = [&](__bf16* lb, int k0) {
    gl_lds16(BT + (col0 + arow) * KK + k0 + aksg * 8, &lb[tid * 8]);
    gl_lds16(BT + (col0 + arow + 64) * KK + k0 + aksg * 8, &lb[(tid + 256) * 8]);
  };
  auto stageAf = [&](__bf16* la, int k0) {
    const float* a0p = &Af[ar0 * KK + k0 + aksg * 8];
    const float* a1p = &Af[ar1 * KK + k0 + aksg * 8];
    const float4 p0 = *(const float4*)a0p, p1 = *(const float4*)(a0p + 4);
    const float4 q0 = *(const float4*)a1p, q1 = *(const float4*)(a1p + 4);
    bf16x8 o0, o1;
    o0[0] = (__bf16)p0.x; o0[1] = (__bf16)p0.y; o0[2] = (__bf16)p0.z; o0[3] = (__bf16)p0.w;
    o0[4] = (__bf16)p1.x; o0[5] = (__bf16)p1.y; o0[6] = (__bf16)p1.z; o0[7] = (__bf16)p1.w;
    o1[0] = (__bf16)q0.x; o1[1] = (__bf16)q0.y; o1[2] = (__bf16)q0.z; o1[3] = (__bf16)q0.w;
    o1[4] = (__bf16)q1.x; o1[5] = (__bf16)q1.y; o1[6] = (__bf16)q1.z; o1[7] = (__bf16)q1.w;
    *(bf16x8*)&la[tid * 8] = o0;
    *(bf16x8*)&la[(tid + 256) * 8] = o1;
  };

  int slA[4], slB[4];
  #pragma unroll
  for (int m = 0; m < 4; m++) {
    const int rm = wr + m * 16 + fr;
    slA[m] = rm * 4 + (ks ^ ((rm >> 1) & 3));
    const int cn = wc + m * 16 + fr;
    slB[m] = cn * 4 + (ks ^ ((cn >> 1) & 3));
  }

  // phases of 64 K each: stage both 32-halves, one wait+barrier, MFMA both.
  #pragma unroll
  for (int ph = 0; ph < KK / 64; ph++) {
    if (ph) __syncthreads();                         // WAR: buffers reused
    const int kb = ph * 64;
    stageAf(bufA(0), kb);
    stageB(bufB(0), kb);
    stageAf(bufA(1), kb + 32);
    stageB(bufB(1), kb + 32);
    asm volatile("s_waitcnt vmcnt(0) lgkmcnt(0)" ::: "memory");
    __builtin_amdgcn_s_barrier();
    #pragma unroll
    for (int t = 0; t < 2; t++) {
      const __bf16* la = bufA(t);
      const __bf16* lb = bufB(t);
      bf16x8 af[4], bfr[4];
      #pragma unroll
      for (int m = 0; m < 4; m++) af[m]  = *(const bf16x8*)&la[slA[m] * 8];
      #pragma unroll
      for (int n = 0; n < 4; n++) bfr[n] = *(const bf16x8*)&lb[slB[n] * 8];
      #pragma unroll
      for (int m = 0; m < 4; m++)
        #pragma unroll
        for (int n = 0; n < 4; n++)
          acc[m][n] = __builtin_amdgcn_mfma_f32_16x16x32_bf16(af[m], bfr[n], acc[m][n], 0, 0, 0);
    }
  }
  __syncthreads();

  // ---- coalesced epilogue (stride-132 sm, float4 readback) ----
  if (tid < 128) sbias[tid] = bias[col0 + tid];
  const int rbase = (wave >> 1) * 16 + ks * 4;
  const int rr = tid >> 3, cs = (tid & 7) * 16;
  #pragma unroll
  for (int m = 0; m < 4; m++) {
    if (m) __syncthreads();
    #pragma unroll
    for (int n = 0; n < 4; n++)
      #pragma unroll
      for (int r = 0; r < 4; r++)
        sm[rbase + r][wc + n * 16 + fr] = acc[m][n][r];
    __syncthreads();
    const size_t lrow = ((rr & 16) ? 64 : 0) + m * 16 + (rr & 15);
    const size_t grow = row0 + lrow;
    float v[16];
    #pragma unroll
    for (int j4 = 0; j4 < 4; j4++) {
      const float4 sv4 = *(const float4*)&sm[rr][cs + j4 * 4];
      v[j4 * 4]     = sv4.x + sbias[cs + j4 * 4];
      v[j4 * 4 + 1] = sv4.y + sbias[cs + j4 * 4 + 1];
      v[j4 * 4 + 2] = sv4.z + sbias[cs + j4 * 4 + 2];
      v[j4 * 4 + 3] = sv4.w + sbias[cs + j4 * 4 + 3];
    }
    const size_t gbase = grow * Nn + col0 + cs;
    if (OBF == 2) {
      #pragma unroll
      for (int j = 0; j < 16; j += 4) {
        float4 o; o.x = v[j]; o.y = v[j + 1]; o.z = v[j + 2]; o.w = v[j + 3];
        *(float4*)&Cf[gbase + j] = o;
      }
    }
    bf16x8 o0, o1;
    #pragma unroll
    for (int j = 0; j < 8; j++) { o0[j] = (__bf16)v[j]; o1[j] = (__bf16)v[8 + j]; }
    *(bf16x8*)&Cb[gbase] = o0;
    *(bf16x8*)&Cb[gbase + 8] = o1;
  }
}

// combined encoders: blocks [0,2048) edge-enc (K=64, A gathered), [2048,2304)
// node-enc (K=128, dual C). 32KB LDS -> 4 blocks/CU.
__global__ __launch_bounds__(256, 4)
void k_encs2(const float* x, const __bf16* enc_wT, const float* enc_b,
             float* h, __bf16* hb,
             const float* ea, const __bf16* ee_wT, const float* ee_b,
             __bf16* e_csr, const int2* csr_es) {
  __shared__ __attribute__((aligned(16))) char smem[32768];
  const int bid = (int)blockIdx.x;
  if (bid < (NE / 128) * (HD / 128)) {
    encs_body<1, 1, DE>(smem, bid, ea, ee_wT, ee_b, nullptr, e_csr, csr_es, HD);
  } else {
    encs_body<2, 0, DIN>(smem, bid - (NE / 128) * (HD / 128), x, enc_wT, enc_b,
                         h, hb, nullptr, HD);
  }
}

// ---------------- MFMA GEMM body (device), 128x128 tile, 3-buf pipeline ----------
template <int RES, int OBF, int STATS>
__device__ __forceinline__
void gemm_body(char* smem, int bid,
               const __bf16* __restrict__ Ab, const __bf16* __restrict__ BT,
               const float* __restrict__ bias, const float* __restrict__ R,
               float* __restrict__ Cf, __bf16* __restrict__ Cb,
               float2* __restrict__ pstats, int M, int Nn, int K) {
  float (*sm)[132] = (float(*)[132])smem;          // 32*132*4 = 16896
  float* sbias     = (float*)(smem + 16896);
  float2 (*pst4)[32] = (float2(*)[32])(smem + 17408);
  const int tid  = threadIdx.x;
  const int lane = tid & 63;
  const int wave = tid >> 6;
  const int ntn  = Nn >> 7;
  const int bn   = (bid >> 3) % ntn;                 // XCD swizzle
  const int bm   = (bid & 7) + ((bid >> 3) / ntn) * 8;
  const size_t row0 = (size_t)bm * 128, col0 = (size_t)bn * 128;
  const int wr = (wave >> 1) * 64, wc = (wave & 1) * 64;
  const int ks = lane >> 4, fr = lane & 15;

  auto bufA = [&](int i) -> __bf16* { return (__bf16*)(smem + i * 8192); };
  auto bufB = [&](int i) -> __bf16* { return (__bf16*)(smem + 24576 + i * 8192); };

  f32x4 acc[4][4] = {};

  const int arow = tid >> 2;
  const int aksg = (tid & 3) ^ ((arow >> 1) & 3);

  auto stageB = [&](__bf16* lb, int k0) {
    gl_lds16(BT + (col0 + arow) * K + k0 + aksg * 8, &lb[tid * 8]);
    gl_lds16(BT + (col0 + arow + 64) * K + k0 + aksg * 8, &lb[(tid + 256) * 8]);
  };
  auto stageA = [&](__bf16* la, int k0) {
    gl_lds16(Ab + (row0 + arow) * K + k0 + aksg * 8, &la[tid * 8]);
    gl_lds16(Ab + (row0 + arow + 64) * K + k0 + aksg * 8, &la[(tid + 256) * 8]);
  };

  int slA[4], slB[4];
  #pragma unroll
  for (int m = 0; m < 4; m++) {
    const int rm = wr + m * 16 + fr;
    slA[m] = rm * 4 + (ks ^ ((rm >> 1) & 3));
    const int cn = wc + m * 16 + fr;
    slB[m] = cn * 4 + (ks ^ ((cn >> 1) & 3));
  }

  const int nk = K / 32;
  stageA(bufA(0), 0); stageB(bufB(0), 0);
  if (nk > 1) { stageA(bufA(1), 32); stageB(bufB(1), 32); }
  for (int t = 0; t < nk; t++) {
    const int rem = nk - 1 - t;
    const int nb3 = (t + 2) % 3;
    if (rem >= 2) { stageA(bufA(nb3), (t + 2) * 32); stageB(bufB(nb3), (t + 2) * 32); }
    if (rem >= 2)      asm volatile("s_waitcnt vmcnt(8)" ::: "memory");
    else if (rem == 1) asm volatile("s_waitcnt vmcnt(4)" ::: "memory");
    else               asm volatile("s_waitcnt vmcnt(0)" ::: "memory");
    __builtin_amdgcn_s_barrier();
    __builtin_amdgcn_sched_barrier(0);
    const __bf16* la = bufA(t % 3);
    const __bf16* lb = bufB(t % 3);
    bf16x8 af[4], bfr[4];
    #pragma unroll
    for (int m = 0; m < 4; m++) af[m]  = *(const bf16x8*)&la[slA[m] * 8];
    #pragma unroll
    for (int n = 0; n < 4; n++) bfr[n] = *(const bf16x8*)&lb[slB[n] * 8];
    #pragma unroll
    for (int m = 0; m < 4; m++)
      #pragma unroll
      for (int n = 0; n < 4; n++)
        acc[m][n] = __builtin_amdgcn_mfma_f32_16x16x32_bf16(af[m], bfr[n], acc[m][n], 0, 0, 0);
    __builtin_amdgcn_s_barrier();
  }
  __syncthreads();

  // ---- coalesced epilogue (stride-132 sm, float4 readback) ----
  if (tid < 128) sbias[tid] = bias[col0 + tid];
  const int rbase = (wave >> 1) * 16 + ks * 4;
  const int rr = tid >> 3, cs = (tid & 7) * 16;
  #pragma unroll
  for (int m = 0; m < 4; m++) {
    if (m) __syncthreads();
    #pragma unroll
    for (int n = 0; n < 4; n++)
      #pragma unroll
      for (int r = 0; r < 4; r++)
        sm[rbase + r][wc + n * 16 + fr] = acc[m][n][r];
    __syncthreads();
    const size_t lrow = ((rr & 16) ? 64 : 0) + m * 16 + (rr & 15);
    const size_t grow = row0 + lrow;
    float v[16];
    #pragma unroll
    for (int j4 = 0; j4 < 4; j4++) {
      const float4 sv4 = *(const float4*)&sm[rr][cs + j4 * 4];
      v[j4 * 4]     = sv4.x + sbias[cs + j4 * 4];
      v[j4 * 4 + 1] = sv4.y + sbias[cs + j4 * 4 + 1];
      v[j4 * 4 + 2] = sv4.z + sbias[cs + j4 * 4 + 2];
      v[j4 * 4 + 3] = sv4.w + sbias[cs + j4 * 4 + 3];
    }
    if (STATS) {
      float ssum = 0.f, ssq = 0.f;
      #pragma unroll
      for (int j = 0; j < 16; j++) { ssum += v[j]; ssq += v[j] * v[j]; }
      #pragma unroll
      for (int o = 1; o < 8; o <<= 1) {
        ssum += __shfl_xor(ssum, o);
        ssq  += __shfl_xor(ssq, o);
      }
      if ((tid & 7) == 0) pst4[m][rr].x = ssum, pst4[m][rr].y = ssq;
    }
    const size_t gbase = grow * Nn + col0 + cs;
    if (RES) {
      #pragma unroll
      for (int j = 0; j < 16; j += 4) {
        const float4 rv = *(const float4*)&R[gbase + j];
        v[j] += rv.x; v[j + 1] += rv.y; v[j + 2] += rv.z; v[j + 3] += rv.w;
      }
    }
    if (OBF == 0 || OBF == 2) {
      #pragma unroll
      for (int j = 0; j < 16; j += 4) {
        float4 o; o.x = v[j]; o.y = v[j + 1]; o.z = v[j + 2]; o.w = v[j + 3];
        *(float4*)&Cf[gbase + j] = o;
      }
    }
    if (OBF == 1 || OBF == 2) {
      bf16x8 o0, o1;
      #pragma unroll
      for (int j = 0; j < 8; j++) { o0[j] = (__bf16)v[j]; o1[j] = (__bf16)v[8 + j]; }
      *(bf16x8*)&Cb[gbase] = o0;
      *(bf16x8*)&Cb[gbase + 8] = o1;
    }
  }
  if (STATS) {
    __syncthreads();
    if (tid < 128) {
      const int lr = tid;
      const int hi = lr >> 6, m2 = (lr >> 4) & 3, rl = lr & 15;
      pstats[(row0 + lr) * ntn + bn] = pst4[m2][(hi << 4) | rl];
    }
  }
}

// GEMM1 wrapper (bf16 A, bf16 C + stats)
__global__ __launch_bounds__(256, 3)
void k_gemm1(const __bf16* A, const __bf16* BT, const float* bias,
             __bf16* Cb, float2* pstats, int M, int Nn, int K) {
  __shared__ __attribute__((aligned(16))) char smem[49152];
  gemm_body<0, 1, 1>(smem, (int)blockIdx.x, A, BT, bias, nullptr,
                     nullptr, Cb, pstats, M, Nn, K);
}

// ---------------- GEMM2 full-row: 32x256 tile; LN(c1) on A-stage; epilogue
// computes h (+res) AND next-layer zb = bf16(relu(LN256(h))) in one pass. ----
template <int RES, int WH>
__global__ __launch_bounds__(256, 3)
void k_gemm2f(const __bf16* __restrict__ c1b, const __bf16* __restrict__ BT,
              const float* __restrict__ bias, const float* __restrict__ R,
              const float2* __restrict__ pstats, const float* __restrict__ gamma,
              const float* __restrict__ beta, const float* __restrict__ g2,
              const float* __restrict__ b2, float* __restrict__ hout,
              __bf16* __restrict__ zout) {
  constexpr int K = HD2;    // 512
  constexpr int NC = HD;    // 256
  __shared__ __attribute__((aligned(16))) char smem[7424 + 36864];
  float* smu  = (float*)smem;                   // 128
  float* sinv = (float*)(smem + 128);           // 128
  float* sg   = (float*)(smem + 256);           // 2048
  float* sb   = (float*)(smem + 2304);          // 2048
  float* sg2  = (float*)(smem + 4352);          // 1024
  float* sb2  = (float*)(smem + 5376);          // 1024
  float* sbias= (float*)(smem + 6400);          // 1024
  char* arena = smem + 7424;
  auto bufA = [&](int i) -> __bf16* { return (__bf16*)(arena + i * 18432); };
  auto bufB = [&](int i) -> __bf16* { return (__bf16*)(arena + i * 18432 + 2048); };
  float (*sm)[268] = (float(*)[268])arena;      // 32*268*4 = 34304 <= 36864

  const int tid = threadIdx.x, lane = tid & 63, wave = tid >> 6;
  const size_t row0 = (size_t)blockIdx.x * 32;
  const int wc = wave * 64;
  const int ks = lane >> 4, fr = lane & 15;

  if (tid < 32) {
    const float4* pp = (const float4*)&pstats[(row0 + tid) * 4];
    const float4 a0 = pp[0], a1 = pp[1];
    const float su = a0.x + a0.z + a1.x + a1.z;
    const float sq = a0.y + a0.w + a1.y + a1.w;
    const float mu = su * (1.f / K);
    smu[tid] = mu;
    sinv[tid] = rsqrtf(sq * (1.f / K) - mu * mu + 1e-5f);
  }
  sg[tid] = gamma[tid]; sg[tid + 256] = gamma[tid + 256];
  sb[tid] = beta[tid];  sb[tid + 256] = beta[tid + 256];
  sg2[tid] = g2[tid]; sb2[tid] = b2[tid]; sbias[tid] = bias[tid];
  __syncthreads();

  const int arow = tid >> 2;                 // A row for t<128 (0..31)
  const int akg  = (tid & 3) ^ ((arow >> 1) & 3);
  f32x4 acc[2][4] = {};
  bf16x8 aReg;

  auto stageB = [&](__bf16* lb, int k0) {
    #pragma unroll
    for (int j = 0; j < 4; j++) {
      const int s = j * 256 + tid;
      const int scol = s >> 2;
      const int kg = (s & 3) ^ ((scol >> 1) & 3);
      gl_lds16(BT + (size_t)scol * K + k0 + kg * 8, &lb[s * 8]);
    }
  };
  auto loadA = [&](int k0) {
    if (tid < 128) aReg = *(const bf16x8*)&c1b[(row0 + arow) * K + k0 + akg * 8];
  };
  auto writeA = [&](__bf16* la, int k0) {
    if (tid < 128) {
      const int kb = k0 + akg * 8;
      const float mu = smu[arow], iv = sinv[arow];
      bf16x8 o;
      #pragma unroll
      for (int j = 0; j < 8; j++) {
        const float f = ((float)aReg[j] - mu) * iv * sg[kb + j] + sb[kb + j];
        o[j] = (__bf16)fmaxf(f, 0.f);
      }
      *(bf16x8*)&la[tid * 8] = o;
    }
  };

  int slA[2], slB[4];
  #pragma unroll
  for (int m = 0; m < 2; m++) {
    const int rm = m * 16 + fr;
    slA[m] = rm * 4 + (ks ^ ((rm >> 1) & 3));
  }
  #pragma unroll
  for (int n = 0; n < 4; n++) {
    const int cn = wc + n * 16 + fr;
    slB[n] = cn * 4 + (ks ^ ((cn >> 1) & 3));
  }

  const int nk = K / 32;   // 16
  loadA(0); stageB(bufB(0), 0); writeA(bufA(0), 0);
  for (int t = 0; t < nk; t++) {
    const bool more = (t + 1 < nk);
    const int cur = t & 1;
    if (more) { stageB(bufB(cur ^ 1), (t + 1) * 32); loadA((t + 1) * 32); }
    if (more) {
      if (wave < 2) asm volatile("s_waitcnt vmcnt(5) lgkmcnt(0)" ::: "memory");
      else          asm volatile("s_waitcnt vmcnt(4) lgkmcnt(0)" ::: "memory");
    } else {
      asm volatile("s_waitcnt vmcnt(0) lgkmcnt(0)" ::: "memory");
    }
    __builtin_amdgcn_s_barrier();
    __builtin_amdgcn_sched_barrier(0);
    const __bf16* la = bufA(cur);
    const __bf16* lb = bufB(cur);
    bf16x8 af[2], bfr[4];
    #pragma unroll
    for (int m = 0; m < 2; m++) af[m]  = *(const bf16x8*)&la[slA[m] * 8];
    #pragma unroll
    for (int n = 0; n < 4; n++) bfr[n] = *(const bf16x8*)&lb[slB[n] * 8];
    #pragma unroll
    for (int m = 0; m < 2; m++)
      #pragma unroll
      for (int n = 0; n < 4; n++)
        acc[m][n] = __builtin_amdgcn_mfma_f32_16x16x32_bf16(af[m], bfr[n], acc[m][n], 0, 0, 0);
    if (more) writeA(bufA(cur ^ 1), (t + 1) * 32);
    __builtin_amdgcn_s_barrier();
  }
  __syncthreads();

  // ---- epilogue: transpose to sm (stride 268), LN over 256 cols, emit h+zb ----
  #pragma unroll
  for (int m = 0; m < 2; m++)
    #pragma unroll
    for (int n = 0; n < 4; n++)
      #pragma unroll
      for (int r = 0; r < 4; r++)
        sm[m * 16 + ks * 4 + r][wc + n * 16 + fr] = acc[m][n][r];
  __syncthreads();
  const int rr = tid >> 3, c0 = (tid & 7) * 4;
  float v[32];
  float s = 0.f, sq = 0.f;
  #pragma unroll
  for (int j = 0; j < 8; j++) {
    const int c = c0 + j * 32;
    const float4 sv4 = *(const float4*)&sm[rr][c];
    float x0 = sv4.x + sbias[c];
    float x1 = sv4.y + sbias[c + 1];
    float x2 = sv4.z + sbias[c + 2];
    float x3 = sv4.w + sbias[c + 3];
    if (RES) {
      const float4 rv = *(const float4*)&R[(row0 + rr) * NC + c];
      x0 += rv.x; x1 += rv.y; x2 += rv.z; x3 += rv.w;
    }
    v[j * 4] = x0; v[j * 4 + 1] = x1; v[j * 4 + 2] = x2; v[j * 4 + 3] = x3;
    s += x0 + x1 + x2 + x3;
    sq += x0 * x0 + x1 * x1 + x2 * x2 + x3 * x3;
  }
  #pragma unroll
  for (int o = 1; o < 8; o <<= 1) { s += __shfl_xor(s, o); sq += __shfl_xor(sq, o); }
  const float mu = s * (1.f / NC);
  const float inv = rsqrtf(sq * (1.f / NC) - mu * mu + 1e-5f);
  #pragma unroll
  for (int j = 0; j < 8; j++) {
    const int c = c0 + j * 32;
    if (WH) {
      float4 o;
      o.x = v[j * 4]; o.y = v[j * 4 + 1]; o.z = v[j * 4 + 2]; o.w = v[j * 4 + 3];
      *(float4*)&hout[(row0 + rr) * NC + c] = o;
    }
    bf16x4 z;
    z[0] = (__bf16)fmaxf((v[j * 4]     - mu) * inv * sg2[c]     + sb2[c],     0.f);
    z[1] = (__bf16)fmaxf((v[j * 4 + 1] - mu) * inv * sg2[c + 1] + sb2[c + 1], 0.f);
    z[2] = (__bf16)fmaxf((v[j * 4 + 2] - mu) * inv * sg2[c + 2] + sb2[c + 2], 0.f);
    z[3] = (__bf16)fmaxf((v[j * 4 + 3] - mu) * inv * sg2[c + 3] + sb2[c + 3], 0.f);
    *(bf16x4*)&zout[(row0 + rr) * NC + c] = z;
  }
}

// ---------------- wave-per-node softmax aggregation (8-deep groups, bf16 zb) ----
__global__ __launch_bounds__(256)
void k_msg(const __bf16* __restrict__ zb, const __bf16* __restrict__ ecsr,
           const int* __restrict__ row_start, const int* __restrict__ deg,
           const int2* __restrict__ csr_es, const float* __restrict__ tvec,
           int layer, __bf16* __restrict__ a1) {
  const int wv   = __builtin_amdgcn_readfirstlane(threadIdx.x >> 6);
  const int lane = threadIdx.x & 63;
  const int node = blockIdx.x * 4 + wv;
  const int st = __builtin_amdgcn_readfirstlane(row_start[node]);
  const int dg = __builtin_amdgcn_readfirstlane(deg[node]);
  const float t = tvec[layer];
  const int f0 = lane * 4;

  int my_src = 0;
  if (lane < dg) my_src = csr_es[st + lane].y;
  const bf16x4 sv = *(const bf16x4*)&zb[(size_t)node * HD + f0];

  float den[4] = {0.f, 0.f, 0.f, 0.f}, agg[4] = {0.f, 0.f, 0.f, 0.f};
  const int dmain = dg < 64 ? dg : 64;
  int j = 0;
  for (; j + 8 <= dmain; j += 8) {
    bf16x4 zv[8], ev[8];
    #pragma unroll
    for (int u = 0; u < 8; u++) {
      const int sn = __builtin_amdgcn_readlane(my_src, j + u);
      zv[u] = *(const bf16x4*)&zb[(size_t)sn * HD + f0];
      ev[u] = *(const bf16x4*)&ecsr[(size_t)(st + j + u) * HD + f0];
    }
    #pragma unroll
    for (int u = 0; u < 8; u++)
      #pragma unroll
      for (int q = 0; q < 4; q++) {
        const float m  = fmaxf((float)zv[u][q] + (float)ev[u][q], 0.f) + 1e-7f;
        const float ex = __expf(m * t);
        den[q] += ex;
        agg[q] += m * ex;
      }
  }
  for (; j + 4 <= dmain; j += 4) {
    bf16x4 zv[4], ev[4];
    #pragma unroll
    for (int u = 0; u < 4; u++) {
      const int sn = __builtin_amdgcn_readlane(my_src, j + u);
      zv[u] = *(const bf16x4*)&zb[(size_t)sn * HD + f0];
      ev[u] = *(const bf16x4*)&ecsr[(size_t)(st + j + u) * HD + f0];
    }
    #pragma unroll
    for (int u = 0; u < 4; u++)
      #pragma unroll
      for (int q = 0; q < 4; q++) {
        const float m  = fmaxf((float)zv[u][q] + (float)ev[u][q], 0.f) + 1e-7f;
        const float ex = __expf(m * t);
        den[q] += ex;
        agg[q] += m * ex;
      }
  }
  for (; j < dmain; j++) {
    const int sn = __builtin_amdgcn_readlane(my_src, j);
    const bf16x4 zv = *(const bf16x4*)&zb[(size_t)sn * HD + f0];
    const bf16x4 ev = *(const bf16x4*)&ecsr[(size_t)(st + j) * HD + f0];
    #pragma unroll
    for (int q = 0; q < 4; q++) {
      const float m  = fmaxf((float)zv[q] + (float)ev[q], 0.f) + 1e-7f;
      const float ex = __expf(m * t);
      den[q] += ex;
      agg[q] += m * ex;
    }
  }
  for (int jj = 64; jj < dg; jj++) {  // cold path
    const int2 pr = csr_es[st + jj];
    const bf16x4 zv = *(const bf16x4*)&zb[(size_t)pr.y * HD + f0];
    const bf16x4 ev = *(const bf16x4*)&ecsr[(size_t)(st + jj) * HD + f0];
    #pragma unroll
    for (int q = 0; q < 4; q++) {
      const float m  = fmaxf((float)zv[q] + (float)ev[q], 0.f) + 1e-7f;
      const float ex = __expf(m * t);
      den[q] += ex;
      agg[q] += m * ex;
    }
  }
  bf16x4 r;
  #pragma unroll
  for (int q = 0; q < 4; q++) {
    const float res = (dg > 0) ? agg[q] / (den[q] + 1e-16f) : 0.f;
    r[q] = (__bf16)(res + (float)sv[q]);
  }
  *(bf16x4*)&a1[(size_t)node * HD + f0] = r;
}

// ---------------- head: out = zb @ lin_w + lin_b ----------------
__global__ __launch_bounds__(256)
void k_head(const __bf16* __restrict__ zb, const float* __restrict__ lw,
            const float* __restrict__ lb, float* __restrict__ out) {
  __shared__ float slw[256 * 16];     // [k][c]
  __shared__ __bf16 srow[16 * 256];
  const int t = threadIdx.x;
  const size_t row0 = (size_t)blockIdx.x * 16;
  #pragma unroll
  for (int j = 0; j < 16; j++) slw[j * 256 + t] = lw[j * 256 + t];
  #pragma unroll
  for (int j = 0; j < 2; j++) {
    const int c = j * 256 + t;
    ((bf16x8*)srow)[c] = ((const bf16x8*)(zb + row0 * 256))[c];
  }
  __syncthreads();
  const int rl = t >> 4, col = t & 15;
  float s = lb[col];
  for (int k0 = 0; k0 < 256; k0 += 8) {
    const bf16x8 zv = *(const bf16x8*)&srow[rl * 256 + k0];
    #pragma unroll
    for (int q = 0; q < 8; q++) s += (float)zv[q] * slw[(k0 + q) * 16 + col];
  }
  out[(row0 + rl) * 16 + col] = s;
}

// ---------------- host launch ----------------
extern "C" void kernel_launch(void* const* d_in, const int* in_sizes, int n_in,
                              void* d_out, int out_size, void* d_ws, size_t ws_size,
                              hipStream_t stream) {
  const float* x     = (const float*)d_in[0];
  const int*   ei    = (const int*)d_in[1];
  const float* ea    = (const float*)d_in[2];
  const float* enc_w = (const float*)d_in[3];
  const float* enc_b = (const float*)d_in[4];
  const float* ee_w  = (const float*)d_in[5];
  const float* ee_b  = (const float*)d_in[6];
  const float* w1    = (const float*)d_in[7];
  const float* b1    = (const float*)d_in[8];
  const float* lng   = (const float*)d_in[9];
  const float* lnb   = (const float*)d_in[10];
  const float* w2    = (const float*)d_in[11];
  const float* b2    = (const float*)d_in[12];
  const float* tvec  = (const float*)d_in[13];
  const float* ng    = (const float*)d_in[14];
  const float* nb    = (const float*)d_in[15];
  const float* lin_w = (const float*)d_in[16];
  const float* lin_b = (const float*)d_in[17];

  uint8_t* p = (uint8_t*)d_ws;
  auto alloc = [&](size_t bytes) { uint8_t* r = p; p += (bytes + 255) & ~(size_t)255; return r; };
  __bf16* e_csr  = (__bf16*)alloc((size_t)NE * HD * 2);
  float*  h      = (float*) alloc((size_t)NN * HD * 4);
  __bf16* hb     = (__bf16*)alloc((size_t)NN * HD * 2);
  __bf16* zb     = (__bf16*)alloc((size_t)NN * HD * 2);
  __bf16* a1     = (__bf16*)alloc((size_t)NN * HD * 2);
  __bf16* c1b    = (__bf16*)alloc((size_t)NN * HD2 * 2);
  float2* pstats = (float2*)alloc((size_t)NN * 4 * 8);
  __bf16* enc_wT = (__bf16*)alloc((size_t)HD * DIN * 2);
  __bf16* ee_wT  = (__bf16*)alloc((size_t)HD * DE * 2);
  __bf16* w1T    = (__bf16*)alloc((size_t)4 * HD2 * HD * 2);
  __bf16* w2T    = (__bf16*)alloc((size_t)4 * HD * HD2 * 2);
  int* deg       = (int*)alloc((size_t)NN * 4);
  int* cursor    = (int*)alloc((size_t)NN * 4);   // contiguous with deg -> one memset
  int* row_start = (int*)alloc((size_t)NN * 4);
  int2* csr_es   = (int2*)alloc((size_t)NE * 8);

  const int* srcp = ei;
  const int* dstp = ei + NE;

  hipMemsetAsync(deg, 0, (size_t)NN * 8, stream);  // deg + cursor

  const int prep_total = DIN * HD + DE * HD + 4 * HD * HD2 + 4 * HD2 * HD + NE;
  k_prep<<<(prep_total + 255) / 256, 256, 0, stream>>>(enc_w, ee_w, w1, w2, dstp, deg,
                                                       enc_wT, ee_wT, w1T, w2T);
  k_scan<<<1, 1024, 0, stream>>>(deg, row_start);
  k_scatter<<<NE / 256, 256, 0, stream>>>(srcp, dstp, row_start, cursor, csr_es);
  k_sortw<<<NN / 4, 256, 0, stream>>>(row_start, deg, csr_es);

  // both encoders in one launch (tiny-K bodies, 4 blocks/CU)
  k_encs2<<<(NE / 128) * (HD / 128) + (NN / 128) * (HD / 128), 256, 0, stream>>>(
      x, enc_wT, enc_b, h, hb, ea, ee_wT, ee_b, e_csr, csr_es);

  for (int i = 0; i < 4; i++) {
    const __bf16* zin = (i == 0) ? hb : zb;
    k_msg<<<NN / 4, 256, 0, stream>>>(zin, e_csr, row_start, deg, csr_es, tvec, i, a1);
    // GEMM1: c1b = bf16(a1 @ w1 + b1) + 512-wide row stats
    k_gemm1<<<(NN / 128) * (HD2 / 128), 256, 0, stream>>>(
        a1, w1T + (size_t)i * HD2 * HD, b1 + (size_t)i * HD2, c1b, pstats, NN, HD2, HD);
    // GEMM2 full-row: h (+res) AND next-layer zb in one epilogue
    const int nidx = (i < 3) ? i + 1 : 0;
    const float* gg = ng + (size_t)nidx * HD;
    const float* bb = nb + (size_t)nidx * HD;
    if (i == 0)
      k_gemm2f<0, 1><<<NN / 32, 256, 0, stream>>>(
          c1b, w2T + (size_t)i * HD * HD2, b2 + (size_t)i * HD, nullptr, pstats,
          lng + (size_t)i * HD2, lnb + (size_t)i * HD2, gg, bb, h, zb);
    else if (i < 3)
      k_gemm2f<1, 1><<<NN / 32, 256, 0, stream>>>(
          c1b, w2T + (size_t)i * HD * HD2, b2 + (size_t)i * HD, h, pstats,
          lng + (size_t)i * HD2, lnb + (size_t)i * HD2, gg, bb, h, zb);
    else
      k_gemm2f<1, 0><<<NN / 32, 256, 0, stream>>>(
          c1b, w2T + (size_t)i * HD * HD2, b2 + (size_t)i * HD, h, pstats,
          lng + (size_t)i * HD2, lnb + (size_t)i * HD2, gg, bb, h, zb);
  }

  k_head<<<NN / 16, 256, 0, stream>>>(zb, lin_w, lin_b, (float*)d_out);
}

// Round 24
// 292.201 us; speedup vs baseline: 1.0372x; 1.0297x over previous
//
#include <hip/hip_runtime.h>
#include <stdint.h>
#include <math.h>

// DeeperGNN forward on MI355X.
// R24 = R23 + bf16 residual stream: h stored bf16 (hb deleted), gemm2f residual
// read + h write bf16. LN stats still on unrounded f32. ~-65MB traffic.

typedef __bf16 bf16x8 __attribute__((ext_vector_type(8)));
typedef __bf16 bf16x4 __attribute__((ext_vector_type(4)));
typedef float  f32x4  __attribute__((ext_vector_type(4)));

constexpr int NN   = 16384;   // nodes
constexpr int NE   = 131072;  // edges
constexpr int DIN  = 128;
constexpr int DE   = 64;
constexpr int HD   = 256;
constexpr int HD2  = 512;

__device__ __forceinline__ void gl_lds16(const __bf16* g, __bf16* l) {
  __builtin_amdgcn_global_load_lds((const __attribute__((address_space(1))) void*)g,
                                   (__attribute__((address_space(3))) void*)l, 16, 0, 0);
}

// ---------------- CSR build ----------------
__global__ __launch_bounds__(1024) void k_scan(const int* __restrict__ deg,
                                               int* __restrict__ row_start) {
  __shared__ int part[1024];
  const int t = threadIdx.x;
  const int base = t * 16;
  int loc[16];
  int s = 0;
  #pragma unroll
  for (int i = 0; i < 16; i++) { loc[i] = s; s += deg[base + i]; }
  part[t] = s;
  __syncthreads();
  for (int off = 1; off < 1024; off <<= 1) {
    int v = (t >= off) ? part[t - off] : 0;
    __syncthreads();
    part[t] += v;
    __syncthreads();
  }
  const int excl = (t == 0) ? 0 : part[t - 1];
  #pragma unroll
  for (int i = 0; i < 16; i++) row_start[base + i] = excl + loc[i];
}

__global__ void k_scatter(const int* __restrict__ src, const int* __restrict__ dst,
                          const int* __restrict__ row_start, int* __restrict__ cursor,
                          int2* __restrict__ csr_es) {
  int e = blockIdx.x * 256 + threadIdx.x;
  if (e >= NE) return;
  const int d = dst[e];
  const int p = atomicAdd(&cursor[d], 1);
  csr_es[row_start[d] + p] = make_int2(e, src[e]);
}

// wave-parallel canonical sort
__global__ __launch_bounds__(256)
void k_sortw(const int* __restrict__ row_start, const int* __restrict__ deg,
             int2* __restrict__ csr_es) {
  const int wv   = threadIdx.x >> 6;
  const int lane = threadIdx.x & 63;
  const int node = blockIdx.x * 4 + wv;
  if (node >= NN) return;
  const int st = __builtin_amdgcn_readfirstlane(row_start[node]);
  const int dg = __builtin_amdgcn_readfirstlane(deg[node]);
  if (dg <= 1) return;
  if (dg <= 64) {
    int2 pr = make_int2(0x7fffffff, 0);
    if (lane < dg) pr = csr_es[st + lane];
    int rank = 0;
    for (int j = 0; j < dg; j++) {
      const int ej = __builtin_amdgcn_readlane(pr.x, j);
      if (lane < dg && ej < pr.x) rank++;
    }
    if (lane < dg) csr_es[st + rank] = pr;
  } else if (lane == 0) {  // cold fallback
    for (int a = 1; a < dg; a++) {
      int2 k = csr_es[st + a];
      int b = a - 1;
      while (b >= 0 && csr_es[st + b].x > k.x) { csr_es[st + b + 1] = csr_es[st + b]; b--; }
      csr_es[st + b + 1] = k;
    }
  }
}

// ---------------- prep: weight transposes + degree histogram ----------------
__global__ void k_prep(const float* __restrict__ enc_w, const float* __restrict__ ee_w,
                       const float* __restrict__ w1, const float* __restrict__ w2,
                       const int* __restrict__ dst, int* __restrict__ deg,
                       __bf16* __restrict__ enc_wT, __bf16* __restrict__ ee_wT,
                       __bf16* __restrict__ w1T, __bf16* __restrict__ w2T) {
  int i = blockIdx.x * 256 + threadIdx.x;
  const int S0 = DIN * HD, S1 = DE * HD, S2 = 4 * HD * HD2, S3 = 4 * HD2 * HD;
  if (i < S0) { int k = i / HD, n = i % HD; enc_wT[n * DIN + k] = (__bf16)enc_w[i]; return; }
  i -= S0;
  if (i < S1) { int k = i / HD, n = i % HD; ee_wT[n * DE + k] = (__bf16)ee_w[i]; return; }
  i -= S1;
  if (i < S2) {
    int l = i / (HD * HD2), r = i % (HD * HD2), k = r / HD2, n = r % HD2;
    w1T[(size_t)l * HD * HD2 + (size_t)n * HD + k] = (__bf16)w1[i]; return;
  }
  i -= S2;
  if (i < S3) {
    int l = i / (HD2 * HD), r = i % (HD2 * HD), k = r / HD, n = r % HD;
    w2T[(size_t)l * HD2 * HD + (size_t)n * HD2 + k] = (__bf16)w2[i]; return;
  }
  i -= S3;
  if (i < NE) { atomicAdd(&deg[dst[i]], 1); return; }
}

// ---------------- encoder GEMM body: tiny-K, all-K staged, no pipeline ----------
// KK = full K (64 or 128). AGAT: gather A rows via es[pos].x. bf16 C only.
template <int AGAT, int KK>
__device__ __forceinline__
void encs_body(char* smem, int bid,
               const float* __restrict__ Af, const __bf16* __restrict__ BT,
               const float* __restrict__ bias, __bf16* __restrict__ Cb,
               const int2* __restrict__ es, int Nn) {
  float (*sm)[132] = (float(*)[132])smem;          // epilogue overlay (16896B)
  float* sbias     = (float*)(smem + 16896);       // 512B
  const int tid  = threadIdx.x;
  const int lane = tid & 63;
  const int wave = tid >> 6;
  const int ntn  = Nn >> 7;
  const int bn   = (bid >> 3) % ntn;                 // XCD swizzle
  const int bm   = (bid & 7) + ((bid >> 3) / ntn) * 8;
  const size_t row0 = (size_t)bm * 128, col0 = (size_t)bn * 128;
  const int wr = (wave >> 1) * 64, wc = (wave & 1) * 64;
  const int ks = lane >> 4, fr = lane & 15;

  auto bufA = [&](int i) -> __bf16* { return (__bf16*)(smem + i * 8192); };
  auto bufB = [&](int i) -> __bf16* { return (__bf16*)(smem + 16384 + i * 8192); };

  f32x4 acc[4][4] = {};

  const int arow = tid >> 2;
  const int aksg = (tid & 3) ^ ((arow >> 1) & 3);
  size_t ar0, ar1;
  if (AGAT) {
    ar0 = (size_t)es[row0 + arow].x;
    ar1 = (size_t)es[row0 + arow + 64].x;
  } else {
    ar0 = row0 + arow;
    ar1 = row0 + arow + 64;
  }

  auto stageB = [&](__bf16* lb, int k0) {
    gl_lds16(BT + (col0 + arow) * KK + k0 + aksg * 8, &lb[tid * 8]);
    gl_lds16(BT + (col0 + arow + 64) * KK + k0 + aksg * 8, &lb[(tid + 256) * 8]);
  };
  auto stageAf = [&](__bf16* la, int k0) {
    const float* a0p = &Af[ar0 * KK + k0 + aksg * 8];
    const float* a1p = &Af[ar1 * KK + k0 + aksg * 8];
    const float4 p0 = *(const float4*)a0p, p1 = *(const float4*)(a0p + 4);
    const float4 q0 = *(const float4*)a1p, q1 = *(const float4*)(a1p + 4);
    bf16x8 o0, o1;
    o0[0] = (__bf16)p0.x; o0[1] = (__bf16)p0.y; o0[2] = (__bf16)p0.z; o0[3] = (__bf16)p0.w;
    o0[4] = (__bf16)p1.x; o0[5] = (__bf16)p1.y; o0[6] = (__bf16)p1.z; o0[7] = (__bf16)p1.w;
    o1[0] = (__bf16)q0.x; o1[1] = (__bf16)q0.y; o1[2] = (__bf16)q0.z; o1[3] = (__bf16)q0.w;
    o1[4] = (__bf16)q1.x; o1[5] = (__bf16)q1.y; o1[6] = (__bf16)q1.z; o1[7] = (__bf16)q1.w;
    *(bf16x8*)&la[tid * 8] = o0;
    *(bf16x8*)&la[(tid + 256) * 8] = o1;
  };

  int slA[4], slB[4];
  #pragma unroll
  for (int m = 0; m < 4; m++) {
    const int rm = wr + m * 16 + fr;
    slA[m] = rm * 4 + (ks ^ ((rm >> 1) & 3));
    const int cn = wc + m * 16 + fr;
    slB[m] = cn * 4 + (ks ^ ((cn >> 1) & 3));
  }

  #pragma unroll
  for (int ph = 0; ph < KK / 64; ph++) {
    if (ph) __syncthreads();                         // WAR: buffers reused
    const int kb = ph * 64;
    stageAf(bufA(0), kb);
    stageB(bufB(0), kb);
    stageAf(bufA(1), kb + 32);
    stageB(bufB(1), kb + 32);
    asm volatile("s_waitcnt vmcnt(0) lgkmcnt(0)" ::: "memory");
    __builtin_amdgcn_s_barrier();
    #pragma unroll
    for (int t = 0; t < 2; t++) {
      const __bf16* la = bufA(t);
      const __bf16* lb = bufB(t);
      bf16x8 af[4], bfr[4];
      #pragma unroll
      for (int m = 0; m < 4; m++) af[m]  = *(const bf16x8*)&la[slA[m] * 8];
      #pragma unroll
      for (int n = 0; n < 4; n++) bfr[n] = *(const bf16x8*)&lb[slB[n] * 8];
      #pragma unroll
      for (int m = 0; m < 4; m++)
        #pragma unroll
        for (int n = 0; n < 4; n++)
          acc[m][n] = __builtin_amdgcn_mfma_f32_16x16x32_bf16(af[m], bfr[n], acc[m][n], 0, 0, 0);
    }
  }
  __syncthreads();

  // ---- coalesced epilogue (stride-132 sm, float4 readback) ----
  if (tid < 128) sbias[tid] = bias[col0 + tid];
  const int rbase = (wave >> 1) * 16 + ks * 4;
  const int rr = tid >> 3, cs = (tid & 7) * 16;
  #pragma unroll
  for (int m = 0; m < 4; m++) {
    if (m) __syncthreads();
    #pragma unroll
    for (int n = 0; n < 4; n++)
      #pragma unroll
      for (int r = 0; r < 4; r++)
        sm[rbase + r][wc + n * 16 + fr] = acc[m][n][r];
    __syncthreads();
    const size_t lrow = ((rr & 16) ? 64 : 0) + m * 16 + (rr & 15);
    const size_t grow = row0 + lrow;
    float v[16];
    #pragma unroll
    for (int j4 = 0; j4 < 4; j4++) {
      const float4 sv4 = *(const float4*)&sm[rr][cs + j4 * 4];
      v[j4 * 4]     = sv4.x + sbias[cs + j4 * 4];
      v[j4 * 4 + 1] = sv4.y + sbias[cs + j4 * 4 + 1];
      v[j4 * 4 + 2] = sv4.z + sbias[cs + j4 * 4 + 2];
      v[j4 * 4 + 3] = sv4.w + sbias[cs + j4 * 4 + 3];
    }
    const size_t gbase = grow * Nn + col0 + cs;
    bf16x8 o0, o1;
    #pragma unroll
    for (int j = 0; j < 8; j++) { o0[j] = (__bf16)v[j]; o1[j] = (__bf16)v[8 + j]; }
    *(bf16x8*)&Cb[gbase] = o0;
    *(bf16x8*)&Cb[gbase + 8] = o1;
  }
}

// combined encoders: blocks [0,2048) edge-enc (K=64, A gathered), [2048,2304)
// node-enc (K=128). 32KB LDS -> 4 blocks/CU. All outputs bf16.
__global__ __launch_bounds__(256, 4)
void k_encs2(const float* x, const __bf16* enc_wT, const float* enc_b,
             __bf16* h,
             const float* ea, const __bf16* ee_wT, const float* ee_b,
             __bf16* e_csr, const int2* csr_es) {
  __shared__ __attribute__((aligned(16))) char smem[32768];
  const int bid = (int)blockIdx.x;
  if (bid < (NE / 128) * (HD / 128)) {
    encs_body<1, DE>(smem, bid, ea, ee_wT, ee_b, e_csr, csr_es, HD);
  } else {
    encs_body<0, DIN>(smem, bid - (NE / 128) * (HD / 128), x, enc_wT, enc_b,
                      h, nullptr, HD);
  }
}

// ---------------- GEMM1: 128x128 tile, 3-buf pipeline, bf16 C + stats ----------
__global__ __launch_bounds__(256, 3)
void k_gemm1(const __bf16* __restrict__ Ab, const __bf16* __restrict__ BT,
             const float* __restrict__ bias, __bf16* __restrict__ Cb,
             float2* __restrict__ pstats, int M, int Nn, int K) {
  __shared__ __attribute__((aligned(16))) char smem[49152];
  float (*sm)[132] = (float(*)[132])smem;
  float* sbias     = (float*)(smem + 16896);
  float2 (*pst4)[32] = (float2(*)[32])(smem + 17408);
  const int tid  = threadIdx.x;
  const int lane = tid & 63;
  const int wave = tid >> 6;
  const int ntn  = Nn >> 7;
  const int bid  = (int)blockIdx.x;
  const int bn   = (bid >> 3) % ntn;                 // XCD swizzle
  const int bm   = (bid & 7) + ((bid >> 3) / ntn) * 8;
  const size_t row0 = (size_t)bm * 128, col0 = (size_t)bn * 128;
  const int wr = (wave >> 1) * 64, wc = (wave & 1) * 64;
  const int ks = lane >> 4, fr = lane & 15;

  auto bufA = [&](int i) -> __bf16* { return (__bf16*)(smem + i * 8192); };
  auto bufB = [&](int i) -> __bf16* { return (__bf16*)(smem + 24576 + i * 8192); };

  f32x4 acc[4][4] = {};

  const int arow = tid >> 2;
  const int aksg = (tid & 3) ^ ((arow >> 1) & 3);

  auto stageB = [&](__bf16* lb, int k0) {
    gl_lds16(BT + (col0 + arow) * K + k0 + aksg * 8, &lb[tid * 8]);
    gl_lds16(BT + (col0 + arow + 64) * K + k0 + aksg * 8, &lb[(tid + 256) * 8]);
  };
  auto stageA = [&](__bf16* la, int k0) {
    gl_lds16(Ab + (row0 + arow) * K + k0 + aksg * 8, &la[tid * 8]);
    gl_lds16(Ab + (row0 + arow + 64) * K + k0 + aksg * 8, &la[(tid + 256) * 8]);
  };

  int slA[4], slB[4];
  #pragma unroll
  for (int m = 0; m < 4; m++) {
    const int rm = wr + m * 16 + fr;
    slA[m] = rm * 4 + (ks ^ ((rm >> 1) & 3));
    const int cn = wc + m * 16 + fr;
    slB[m] = cn * 4 + (ks ^ ((cn >> 1) & 3));
  }

  const int nk = K / 32;
  stageA(bufA(0), 0); stageB(bufB(0), 0);
  if (nk > 1) { stageA(bufA(1), 32); stageB(bufB(1), 32); }
  for (int t = 0; t < nk; t++) {
    const int rem = nk - 1 - t;
    const int nb3 = (t + 2) % 3;
    if (rem >= 2) { stageA(bufA(nb3), (t + 2) * 32); stageB(bufB(nb3), (t + 2) * 32); }
    if (rem >= 2)      asm volatile("s_waitcnt vmcnt(8)" ::: "memory");
    else if (rem == 1) asm volatile("s_waitcnt vmcnt(4)" ::: "memory");
    else               asm volatile("s_waitcnt vmcnt(0)" ::: "memory");
    __builtin_amdgcn_s_barrier();
    __builtin_amdgcn_sched_barrier(0);
    const __bf16* la = bufA(t % 3);
    const __bf16* lb = bufB(t % 3);
    bf16x8 af[4], bfr[4];
    #pragma unroll
    for (int m = 0; m < 4; m++) af[m]  = *(const bf16x8*)&la[slA[m] * 8];
    #pragma unroll
    for (int n = 0; n < 4; n++) bfr[n] = *(const bf16x8*)&lb[slB[n] * 8];
    #pragma unroll
    for (int m = 0; m < 4; m++)
      #pragma unroll
      for (int n = 0; n < 4; n++)
        acc[m][n] = __builtin_amdgcn_mfma_f32_16x16x32_bf16(af[m], bfr[n], acc[m][n], 0, 0, 0);
    __builtin_amdgcn_s_barrier();
  }
  __syncthreads();

  // ---- coalesced epilogue (stride-132 sm, float4 readback) ----
  if (tid < 128) sbias[tid] = bias[col0 + tid];
  const int rbase = (wave >> 1) * 16 + ks * 4;
  const int rr = tid >> 3, cs = (tid & 7) * 16;
  #pragma unroll
  for (int m = 0; m < 4; m++) {
    if (m) __syncthreads();
    #pragma unroll
    for (int n = 0; n < 4; n++)
      #pragma unroll
      for (int r = 0; r < 4; r++)
        sm[rbase + r][wc + n * 16 + fr] = acc[m][n][r];
    __syncthreads();
    const size_t lrow = ((rr & 16) ? 64 : 0) + m * 16 + (rr & 15);
    const size_t grow = row0 + lrow;
    float v[16];
    #pragma unroll
    for (int j4 = 0; j4 < 4; j4++) {
      const float4 sv4 = *(const float4*)&sm[rr][cs + j4 * 4];
      v[j4 * 4]     = sv4.x + sbias[cs + j4 * 4];
      v[j4 * 4 + 1] = sv4.y + sbias[cs + j4 * 4 + 1];
      v[j4 * 4 + 2] = sv4.z + sbias[cs + j4 * 4 + 2];
      v[j4 * 4 + 3] = sv4.w + sbias[cs + j4 * 4 + 3];
    }
    float ssum = 0.f, ssq = 0.f;
    #pragma unroll
    for (int j = 0; j < 16; j++) { ssum += v[j]; ssq += v[j] * v[j]; }
    #pragma unroll
    for (int o = 1; o < 8; o <<= 1) {
      ssum += __shfl_xor(ssum, o);
      ssq  += __shfl_xor(ssq, o);
    }
    if ((tid & 7) == 0) pst4[m][rr].x = ssum, pst4[m][rr].y = ssq;
    const size_t gbase = grow * Nn + col0 + cs;
    bf16x8 o0, o1;
    #pragma unroll
    for (int j = 0; j < 8; j++) { o0[j] = (__bf16)v[j]; o1[j] = (__bf16)v[8 + j]; }
    *(bf16x8*)&Cb[gbase] = o0;
    *(bf16x8*)&Cb[gbase + 8] = o1;
  }
  __syncthreads();
  if (tid < 128) {
    const int lr = tid;
    const int hi = lr >> 6, m2 = (lr >> 4) & 3, rl = lr & 15;
    pstats[(row0 + lr) * ntn + bn] = pst4[m2][(hi << 4) | rl];
  }
}

// ---------------- GEMM2 full-row: 32x256 tile; LN(c1) on A-stage; epilogue
// computes h (+res, bf16) AND next-layer zb = bf16(relu(LN256(h))) in one pass.
template <int RES, int WH>
__global__ __launch_bounds__(256, 3)
void k_gemm2f(const __bf16* __restrict__ c1b, const __bf16* __restrict__ BT,
              const float* __restrict__ bias, const __bf16* __restrict__ R,
              const float2* __restrict__ pstats, const float* __restrict__ gamma,
              const float* __restrict__ beta, const float* __restrict__ g2,
              const float* __restrict__ b2, __bf16* __restrict__ hout,
              __bf16* __restrict__ zout) {
  constexpr int K = HD2;    // 512
  constexpr int NC = HD;    // 256
  __shared__ __attribute__((aligned(16))) char smem[7424 + 36864];
  float* smu  = (float*)smem;                   // 128
  float* sinv = (float*)(smem + 128);           // 128
  float* sg   = (float*)(smem + 256);           // 2048
  float* sb   = (float*)(smem + 2304);          // 2048
  float* sg2  = (float*)(smem + 4352);          // 1024
  float* sb2  = (float*)(smem + 5376);          // 1024
  float* sbias= (float*)(smem + 6400);          // 1024
  char* arena = smem + 7424;
  auto bufA = [&](int i) -> __bf16* { return (__bf16*)(arena + i * 18432); };
  auto bufB = [&](int i) -> __bf16* { return (__bf16*)(arena + i * 18432 + 2048); };
  float (*sm)[268] = (float(*)[268])arena;      // 32*268*4 = 34304 <= 36864

  const int tid = threadIdx.x, lane = tid & 63, wave = tid >> 6;
  const size_t row0 = (size_t)blockIdx.x * 32;
  const int wc = wave * 64;
  const int ks = lane >> 4, fr = lane & 15;

  if (tid < 32) {
    const float4* pp = (const float4*)&pstats[(row0 + tid) * 4];
    const float4 a0 = pp[0], a1 = pp[1];
    const float su = a0.x + a0.z + a1.x + a1.z;
    const float sq = a0.y + a0.w + a1.y + a1.w;
    const float mu = su * (1.f / K);
    smu[tid] = mu;
    sinv[tid] = rsqrtf(sq * (1.f / K) - mu * mu + 1e-5f);
  }
  sg[tid] = gamma[tid]; sg[tid + 256] = gamma[tid + 256];
  sb[tid] = beta[tid];  sb[tid + 256] = beta[tid + 256];
  sg2[tid] = g2[tid]; sb2[tid] = b2[tid]; sbias[tid] = bias[tid];
  __syncthreads();

  const int arow = tid >> 2;                 // A row for t<128 (0..31)
  const int akg  = (tid & 3) ^ ((arow >> 1) & 3);
  f32x4 acc[2][4] = {};
  bf16x8 aReg;

  auto stageB = [&](__bf16* lb, int k0) {
    #pragma unroll
    for (int j = 0; j < 4; j++) {
      const int s = j * 256 + tid;
      const int scol = s >> 2;
      const int kg = (s & 3) ^ ((scol >> 1) & 3);
      gl_lds16(BT + (size_t)scol * K + k0 + kg * 8, &lb[s * 8]);
    }
  };
  auto loadA = [&](int k0) {
    if (tid < 128) aReg = *(const bf16x8*)&c1b[(row0 + arow) * K + k0 + akg * 8];
  };
  auto writeA = [&](__bf16* la, int k0) {
    if (tid < 128) {
      const int kb = k0 + akg * 8;
      const float mu = smu[arow], iv = sinv[arow];
      bf16x8 o;
      #pragma unroll
      for (int j = 0; j < 8; j++) {
        const float f = ((float)aReg[j] - mu) * iv * sg[kb + j] + sb[kb + j];
        o[j] = (__bf16)fmaxf(f, 0.f);
      }
      *(bf16x8*)&la[tid * 8] = o;
    }
  };

  int slA[2], slB[4];
  #pragma unroll
  for (int m = 0; m < 2; m++) {
    const int rm = m * 16 + fr;
    slA[m] = rm * 4 + (ks ^ ((rm >> 1) & 3));
  }
  #pragma unroll
  for (int n = 0; n < 4; n++) {
    const int cn = wc + n * 16 + fr;
    slB[n] = cn * 4 + (ks ^ ((cn >> 1) & 3));
  }

  const int nk = K / 32;   // 16
  loadA(0); stageB(bufB(0), 0); writeA(bufA(0), 0);
  for (int t = 0; t < nk; t++) {
    const bool more = (t + 1 < nk);
    const int cur = t & 1;
    if (more) { stageB(bufB(cur ^ 1), (t + 1) * 32); loadA((t + 1) * 32); }
    if (more) {
      if (wave < 2) asm volatile("s_waitcnt vmcnt(5) lgkmcnt(0)" ::: "memory");
      else          asm volatile("s_waitcnt vmcnt(4) lgkmcnt(0)" ::: "memory");
    } else {
      asm volatile("s_waitcnt vmcnt(0) lgkmcnt(0)" ::: "memory");
    }
    __builtin_amdgcn_s_barrier();
    __builtin_amdgcn_sched_barrier(0);
    const __bf16* la = bufA(cur);
    const __bf16* lb = bufB(cur);
    bf16x8 af[2], bfr[4];
    #pragma unroll
    for (int m = 0; m < 2; m++) af[m]  = *(const bf16x8*)&la[slA[m] * 8];
    #pragma unroll
    for (int n = 0; n < 4; n++) bfr[n] = *(const bf16x8*)&lb[slB[n] * 8];
    #pragma unroll
    for (int m = 0; m < 2; m++)
      #pragma unroll
      for (int n = 0; n < 4; n++)
        acc[m][n] = __builtin_amdgcn_mfma_f32_16x16x32_bf16(af[m], bfr[n], acc[m][n], 0, 0, 0);
    if (more) writeA(bufA(cur ^ 1), (t + 1) * 32);
    __builtin_amdgcn_s_barrier();
  }
  __syncthreads();

  // ---- epilogue: transpose to sm (stride 268), LN over 256 cols, emit h+zb ----
  #pragma unroll
  for (int m = 0; m < 2; m++)
    #pragma unroll
    for (int n = 0; n < 4; n++)
      #pragma unroll
      for (int r = 0; r < 4; r++)
        sm[m * 16 + ks * 4 + r][wc + n * 16 + fr] = acc[m][n][r];
  __syncthreads();
  const int rr = tid >> 3, c0 = (tid & 7) * 4;
  float v[32];
  float s = 0.f, sq = 0.f;
  #pragma unroll
  for (int j = 0; j < 8; j++) {
    const int c = c0 + j * 32;
    const float4 sv4 = *(const float4*)&sm[rr][c];
    float x0 = sv4.x + sbias[c];
    float x1 = sv4.y + sbias[c + 1];
    float x2 = sv4.z + sbias[c + 2];
    float x3 = sv4.w + sbias[c + 3];
    if (RES) {
      const bf16x4 rv = *(const bf16x4*)&R[(row0 + rr) * NC + c];
      x0 += (float)rv[0]; x1 += (float)rv[1]; x2 += (float)rv[2]; x3 += (float)rv[3];
    }
    v[j * 4] = x0; v[j * 4 + 1] = x1; v[j * 4 + 2] = x2; v[j * 4 + 3] = x3;
    s += x0 + x1 + x2 + x3;
    sq += x0 * x0 + x1 * x1 + x2 * x2 + x3 * x3;
  }
  #pragma unroll
  for (int o = 1; o < 8; o <<= 1) { s += __shfl_xor(s, o); sq += __shfl_xor(sq, o); }
  const float mu = s * (1.f / NC);
  const float inv = rsqrtf(sq * (1.f / NC) - mu * mu + 1e-5f);
  #pragma unroll
  for (int j = 0; j < 8; j++) {
    const int c = c0 + j * 32;
    if (WH) {
      bf16x4 o;
      o[0] = (__bf16)v[j * 4];     o[1] = (__bf16)v[j * 4 + 1];
      o[2] = (__bf16)v[j * 4 + 2]; o[3] = (__bf16)v[j * 4 + 3];
      *(bf16x4*)&hout[(row0 + rr) * NC + c] = o;
    }
    bf16x4 z;
    z[0] = (__bf16)fmaxf((v[j * 4]     - mu) * inv * sg2[c]     + sb2[c],     0.f);
    z[1] = (__bf16)fmaxf((v[j * 4 + 1] - mu) * inv * sg2[c + 1] + sb2[c + 1], 0.f);
    z[2] = (__bf16)fmaxf((v[j * 4 + 2] - mu) * inv * sg2[c + 2] + sb2[c + 2], 0.f);
    z[3] = (__bf16)fmaxf((v[j * 4 + 3] - mu) * inv * sg2[c + 3] + sb2[c + 3], 0.f);
    *(bf16x4*)&zout[(row0 + rr) * NC + c] = z;
  }
}

// ---------------- wave-per-node softmax aggregation (8-deep groups, bf16 zb) ----
__global__ __launch_bounds__(256)
void k_msg(const __bf16* __restrict__ zb, const __bf16* __restrict__ ecsr,
           const int* __restrict__ row_start, const int* __restrict__ deg,
           const int2* __restrict__ csr_es, const float* __restrict__ tvec,
           int layer, __bf16* __restrict__ a1) {
  const int wv   = __builtin_amdgcn_readfirstlane(threadIdx.x >> 6);
  const int lane = threadIdx.x & 63;
  const int node = blockIdx.x * 4 + wv;
  const int st = __builtin_amdgcn_readfirstlane(row_start[node]);
  const int dg = __builtin_amdgcn_readfirstlane(deg[node]);
  const float t = tvec[layer];
  const int f0 = lane * 4;

  int my_src = 0;
  if (lane < dg) my_src = csr_es[st + lane].y;
  const bf16x4 sv = *(const bf16x4*)&zb[(size_t)node * HD + f0];

  float den[4] = {0.f, 0.f, 0.f, 0.f}, agg[4] = {0.f, 0.f, 0.f, 0.f};
  const int dmain = dg < 64 ? dg : 64;
  int j = 0;
  for (; j + 8 <= dmain; j += 8) {
    bf16x4 zv[8], ev[8];
    #pragma unroll
    for (int u = 0; u < 8; u++) {
      const int sn = __builtin_amdgcn_readlane(my_src, j + u);
      zv[u] = *(const bf16x4*)&zb[(size_t)sn * HD + f0];
      ev[u] = *(const bf16x4*)&ecsr[(size_t)(st + j + u) * HD + f0];
    }
    #pragma unroll
    for (int u = 0; u < 8; u++)
      #pragma unroll
      for (int q = 0; q < 4; q++) {
        const float m  = fmaxf((float)zv[u][q] + (float)ev[u][q], 0.f) + 1e-7f;
        const float ex = __expf(m * t);
        den[q] += ex;
        agg[q] += m * ex;
      }
  }
  for (; j + 4 <= dmain; j += 4) {
    bf16x4 zv[4], ev[4];
    #pragma unroll
    for (int u = 0; u < 4; u++) {
      const int sn = __builtin_amdgcn_readlane(my_src, j + u);
      zv[u] = *(const bf16x4*)&zb[(size_t)sn * HD + f0];
      ev[u] = *(const bf16x4*)&ecsr[(size_t)(st + j + u) * HD + f0];
    }
    #pragma unroll
    for (int u = 0; u < 4; u++)
      #pragma unroll
      for (int q = 0; q < 4; q++) {
        const float m  = fmaxf((float)zv[u][q] + (float)ev[u][q], 0.f) + 1e-7f;
        const float ex = __expf(m * t);
        den[q] += ex;
        agg[q] += m * ex;
      }
  }
  for (; j < dmain; j++) {
    const int sn = __builtin_amdgcn_readlane(my_src, j);
    const bf16x4 zv = *(const bf16x4*)&zb[(size_t)sn * HD + f0];
    const bf16x4 ev = *(const bf16x4*)&ecsr[(size_t)(st + j) * HD + f0];
    #pragma unroll
    for (int q = 0; q < 4; q++) {
      const float m  = fmaxf((float)zv[q] + (float)ev[q], 0.f) + 1e-7f;
      const float ex = __expf(m * t);
      den[q] += ex;
      agg[q] += m * ex;
    }
  }
  for (int jj = 64; jj < dg; jj++) {  // cold path
    const int2 pr = csr_es[st + jj];
    const bf16x4 zv = *(const bf16x4*)&zb[(size_t)pr.y * HD + f0];
    const bf16x4 ev = *(const bf16x4*)&ecsr[(size_t)(st + jj) * HD + f0];
    #pragma unroll
    for (int q = 0; q < 4; q++) {
      const float m  = fmaxf((float)zv[q] + (float)ev[q], 0.f) + 1e-7f;
      const float ex = __expf(m * t);
      den[q] += ex;
      agg[q] += m * ex;
    }
  }
  bf16x4 r;
  #pragma unroll
  for (int q = 0; q < 4; q++) {
    const float res = (dg > 0) ? agg[q] / (den[q] + 1e-16f) : 0.f;
    r[q] = (__bf16)(res + (float)sv[q]);
  }
  *(bf16x4*)&a1[(size_t)node * HD + f0] = r;
}

// ---------------- head: out = zb @ lin_w + lin_b ----------------
__global__ __launch_bounds__(256)
void k_head(const __bf16* __restrict__ zb, const float* __restrict__ lw,
            const float* __restrict__ lb, float* __restrict__ out) {
  __shared__ float slw[256 * 16];     // [k][c]
  __shared__ __bf16 srow[16 * 256];
  const int t = threadIdx.x;
  const size_t row0 = (size_t)blockIdx.x * 16;
  #pragma unroll
  for (int j = 0; j < 16; j++) slw[j * 256 + t] = lw[j * 256 + t];
  #pragma unroll
  for (int j = 0; j < 2; j++) {
    const int c = j * 256 + t;
    ((bf16x8*)srow)[c] = ((const bf16x8*)(zb + row0 * 256))[c];
  }
  __syncthreads();
  const int rl = t >> 4, col = t & 15;
  float s = lb[col];
  for (int k0 = 0; k0 < 256; k0 += 8) {
    const bf16x8 zv = *(const bf16x8*)&srow[rl * 256 + k0];
    #pragma unroll
    for (int q = 0; q < 8; q++) s += (float)zv[q] * slw[(k0 + q) * 16 + col];
  }
  out[(row0 + rl) * 16 + col] = s;
}

// ---------------- host launch ----------------
extern "C" void kernel_launch(void* const* d_in, const int* in_sizes, int n_in,
                              void* d_out, int out_size, void* d_ws, size_t ws_size,
                              hipStream_t stream) {
  const float* x     = (const float*)d_in[0];
  const int*   ei    = (const int*)d_in[1];
  const float* ea    = (const float*)d_in[2];
  const float* enc_w = (const float*)d_in[3];
  const float* enc_b = (const float*)d_in[4];
  const float* ee_w  = (const float*)d_in[5];
  const float* ee_b  = (const float*)d_in[6];
  const float* w1    = (const float*)d_in[7];
  const float* b1    = (const float*)d_in[8];
  const float* lng   = (const float*)d_in[9];
  const float* lnb   = (const float*)d_in[10];
  const float* w2    = (const float*)d_in[11];
  const float* b2    = (const float*)d_in[12];
  const float* tvec  = (const float*)d_in[13];
  const float* ng    = (const float*)d_in[14];
  const float* nb    = (const float*)d_in[15];
  const float* lin_w = (const float*)d_in[16];
  const float* lin_b = (const float*)d_in[17];

  uint8_t* p = (uint8_t*)d_ws;
  auto alloc = [&](size_t bytes) { uint8_t* r = p; p += (bytes + 255) & ~(size_t)255; return r; };
  __bf16* e_csr  = (__bf16*)alloc((size_t)NE * HD * 2);
  __bf16* h      = (__bf16*)alloc((size_t)NN * HD * 2);
  __bf16* zb     = (__bf16*)alloc((size_t)NN * HD * 2);
  __bf16* a1     = (__bf16*)alloc((size_t)NN * HD * 2);
  __bf16* c1b    = (__bf16*)alloc((size_t)NN * HD2 * 2);
  float2* pstats = (float2*)alloc((size_t)NN * 4 * 8);
  __bf16* enc_wT = (__bf16*)alloc((size_t)HD * DIN * 2);
  __bf16* ee_wT  = (__bf16*)alloc((size_t)HD * DE * 2);
  __bf16* w1T    = (__bf16*)alloc((size_t)4 * HD2 * HD * 2);
  __bf16* w2T    = (__bf16*)alloc((size_t)4 * HD * HD2 * 2);
  int* deg       = (int*)alloc((size_t)NN * 4);
  int* cursor    = (int*)alloc((size_t)NN * 4);   // contiguous with deg -> one memset
  int* row_start = (int*)alloc((size_t)NN * 4);
  int2* csr_es   = (int2*)alloc((size_t)NE * 8);

  const int* srcp = ei;
  const int* dstp = ei + NE;

  hipMemsetAsync(deg, 0, (size_t)NN * 8, stream);  // deg + cursor

  const int prep_total = DIN * HD + DE * HD + 4 * HD * HD2 + 4 * HD2 * HD + NE;
  k_prep<<<(prep_total + 255) / 256, 256, 0, stream>>>(enc_w, ee_w, w1, w2, dstp, deg,
                                                       enc_wT, ee_wT, w1T, w2T);
  k_scan<<<1, 1024, 0, stream>>>(deg, row_start);
  k_scatter<<<NE / 256, 256, 0, stream>>>(srcp, dstp, row_start, cursor, csr_es);
  k_sortw<<<NN / 4, 256, 0, stream>>>(row_start, deg, csr_es);

  // both encoders in one launch (tiny-K bodies, 4 blocks/CU), bf16 outputs
  k_encs2<<<(NE / 128) * (HD / 128) + (NN / 128) * (HD / 128), 256, 0, stream>>>(
      x, enc_wT, enc_b, h, ea, ee_wT, ee_b, e_csr, csr_es);

  for (int i = 0; i < 4; i++) {
    const __bf16* zin = (i == 0) ? h : zb;
    k_msg<<<NN / 4, 256, 0, stream>>>(zin, e_csr, row_start, deg, csr_es, tvec, i, a1);
    // GEMM1: c1b = bf16(a1 @ w1 + b1) + 512-wide row stats
    k_gemm1<<<(NN / 128) * (HD2 / 128), 256, 0, stream>>>(
        a1, w1T + (size_t)i * HD2 * HD, b1 + (size_t)i * HD2, c1b, pstats, NN, HD2, HD);
    // GEMM2 full-row: h (+res, bf16) AND next-layer zb in one epilogue
    const int nidx = (i < 3) ? i + 1 : 0;
    const float* gg = ng + (size_t)nidx * HD;
    const float* bb = nb + (size_t)nidx * HD;
    if (i == 0)
      k_gemm2f<0, 1><<<NN / 32, 256, 0, stream>>>(
          c1b, w2T + (size_t)i * HD * HD2, b2 + (size_t)i * HD, nullptr, pstats,
          lng + (size_t)i * HD2, lnb + (size_t)i * HD2, gg, bb, h, zb);
    else if (i < 3)
      k_gemm2f<1, 1><<<NN / 32, 256, 0, stream>>>(
          c1b, w2T + (size_t)i * HD * HD2, b2 + (size_t)i * HD, h, pstats,
          lng + (size_t)i * HD2, lnb + (size_t)i * HD2, gg, bb, h, zb);
    else
      k_gemm2f<1, 0><<<NN / 32, 256, 0, stream>>>(
          c1b, w2T + (size_t)i * HD * HD2, b2 + (size_t)i * HD, h, pstats,
          lng + (size_t)i * HD2, lnb + (size_t)i * HD2, gg, bb, h, zb);
  }

  k_head<<<NN / 16, 256, 0, stream>>>(zb, lin_w, lin_b, (float*)d_out);
}